// Round 6
// baseline (2689.271 us; speedup 1.0000x reference)
//
#include <hip/hip_runtime.h>
#include <math.h>

#define PLANE (512*512)

typedef short bf16x8 __attribute__((ext_vector_type(8)));
typedef float f32x4 __attribute__((ext_vector_type(4)));

// fast GELU: 0.5*x*(1+erf(x/sqrt(2))), erf via Abramowitz-Stegun 7.1.26 (|err|<=1.5e-7)
__device__ __forceinline__ float gelu_f(float x) {
    float ax = fabsf(x) * 0.70710678118654752440f;   // z = |x|/sqrt(2)
    float t = __builtin_amdgcn_rcpf(1.0f + 0.3275911f * ax);
    float poly = t * (0.254829592f + t * (-0.284496736f + t * (1.421413741f
               + t * (-1.453152027f + t * 1.061405429f))));
    float e = __expf(-ax * ax);
    float er = 1.0f - poly * e;
    er = copysignf(er, x);
    return 0.5f * x * (1.0f + er);
}

__device__ __forceinline__ unsigned short f2bf(float f) {
    union { float f; unsigned u; } v; v.f = f;
    unsigned r = v.u + 0x7FFFu + ((v.u >> 16) & 1u);
    return (unsigned short)(r >> 16);
}

// ---------------- K1: LayerNorm over channels (64) ----------------
__global__ __launch_bounds__(128) void k_ln(const float* __restrict__ sc,
                                            const float* __restrict__ lnw,
                                            const float* __restrict__ lnb,
                                            float* __restrict__ sn) {
    __shared__ float tile[64 * 128];
    int tid = threadIdx.x;
    int p = blockIdx.x * 128 + tid;       // 0 .. 524287
    int b = p >> 18;
    int hw = p & (PLANE - 1);
    const float* src = sc + (size_t)b * 64 * PLANE + hw;
    float sum = 0.f, sq = 0.f;
    #pragma unroll 8
    for (int c = 0; c < 64; ++c) {
        float v = src[(size_t)c * PLANE];
        tile[c * 128 + tid] = v;
        sum += v; sq += v * v;
    }
    float mu = sum * (1.0f / 64.0f);
    float var = sq * (1.0f / 64.0f) - mu * mu;
    float rstd = rsqrtf(var + 1e-5f);
    float* dst = sn + (size_t)b * 64 * PLANE + hw;
    #pragma unroll 8
    for (int c = 0; c < 64; ++c) {
        float v = tile[c * 128 + tid];
        dst[(size_t)c * PLANE] = (v - mu) * rstd * lnw[c] + lnb[c];
    }
}

// ---------------- K2: depthwise 3x3 (64ch) + BN + GELU ----------------
__global__ __launch_bounds__(256) void k_dw64(const float* __restrict__ in,
                                              const float* __restrict__ wt,
                                              const float* __restrict__ bns,
                                              const float* __restrict__ bnt,
                                              float* __restrict__ out) {
    int idx = blockIdx.x * 256 + threadIdx.x;   // over 2*64*PLANE
    int w = idx & 511;
    int h = (idx >> 9) & 511;
    int bc = idx >> 18;
    int c = bc & 63;
    const float* ip = in + (size_t)bc * PLANE;
    const float* wp = wt + c * 9;
    float acc = 0.f;
    #pragma unroll
    for (int dh = -1; dh <= 1; ++dh) {
        int hh = h + dh; if (hh < 0 || hh > 511) continue;
        #pragma unroll
        for (int dw = -1; dw <= 1; ++dw) {
            int ww = w + dw; if (ww < 0 || ww > 511) continue;
            acc += wp[(dh + 1) * 3 + (dw + 1)] * ip[hh * 512 + ww];
        }
    }
    out[idx] = gelu_f(acc * bns[c] + bnt[c]);
}

// ---------------- K3: per-pixel pw 64->128 (+gelu) -> split; v = bn(pw 64->128) ----------------
__global__ __launch_bounds__(256) void k_pw_kv(const float* __restrict__ t1,
                                               const float* __restrict__ W1,
                                               const float* __restrict__ b1,
                                               const float* __restrict__ W2,
                                               const float* __restrict__ vbs,
                                               const float* __restrict__ vbt,
                                               float* __restrict__ k_in,
                                               float* __restrict__ v) {
    __shared__ float Wl[128 * 64];
    __shared__ float pb[128], ps[128], pt[128];
    int tid = threadIdx.x;
    int p = blockIdx.x * 256 + tid;
    int b = p >> 18;
    int hw = p & (PLANE - 1);
    for (int i = tid; i < 8192; i += 256) Wl[i] = W1[i];
    if (tid < 128) { pb[tid] = b1[tid]; ps[tid] = vbs[tid]; pt[tid] = vbt[tid]; }
    float t1r[64];
    const float* tp = t1 + (size_t)b * 64 * PLANE + hw;
    #pragma unroll
    for (int i = 0; i < 64; ++i) t1r[i] = tp[(size_t)i * PLANE];
    __syncthreads();
    float vin[64];
    float* kp = k_in + (size_t)b * 64 * PLANE + hw;
    for (int o = 0; o < 128; ++o) {
        float acc = pb[o];
        const float4* wr = (const float4*)&Wl[o * 64];
        #pragma unroll
        for (int i4 = 0; i4 < 16; ++i4) {
            float4 wv = wr[i4];
            acc += wv.x * t1r[i4 * 4 + 0] + wv.y * t1r[i4 * 4 + 1]
                 + wv.z * t1r[i4 * 4 + 2] + wv.w * t1r[i4 * 4 + 3];
        }
        float g = gelu_f(acc);
        if (o < 64) kp[(size_t)o * PLANE] = g;
        else        vin[o - 64] = g;
    }
    __syncthreads();
    for (int i = tid; i < 8192; i += 256) Wl[i] = W2[i];
    __syncthreads();
    float* vp = v + (size_t)b * 128 * PLANE + hw;
    for (int o = 0; o < 128; ++o) {
        float acc = 0.f;
        const float4* wr = (const float4*)&Wl[o * 64];
        #pragma unroll
        for (int i4 = 0; i4 < 16; ++i4) {
            float4 wv = wr[i4];
            acc += wv.x * vin[i4 * 4 + 0] + wv.y * vin[i4 * 4 + 1]
                 + wv.z * vin[i4 * 4 + 2] + wv.w * vin[i4 * 4 + 3];
        }
        vp[(size_t)o * PLANE] = acc * ps[o] + pt[o];
    }
}

// ---------------- K4/K5: grouped dw 3x3 (64->128) + BN + GELU, emit row/col pooled sums only ----------------
__global__ __launch_bounds__(512) void k_dwpool(const float* __restrict__ in,
                                                const float* __restrict__ wt,
                                                const float* __restrict__ bns,
                                                const float* __restrict__ bnt,
                                                float* __restrict__ rowsum,   // (B,128,512)
                                                float* __restrict__ colpart) { // (B,128,64,512)
    __shared__ float lred[2][8][8];
    int tid = threadIdx.x;
    int blk = blockIdx.x;            // (b*64+g)*64+hc
    int hc = blk & 63;
    int g  = (blk >> 6) & 63;
    int b  = blk >> 12;
    int o0 = 2 * g, o1 = 2 * g + 1;
    const float* ip = in + ((size_t)b * 64 + g) * PLANE;
    float w0[9], w1[9];
    #pragma unroll
    for (int k = 0; k < 9; ++k) { w0[k] = wt[o0 * 9 + k]; w1[k] = wt[o1 * 9 + k]; }
    float s0 = bns[o0], t0 = bnt[o0], s1 = bns[o1], tt1 = bnt[o1];
    int wx = tid;
    float ca0 = 0.f, ca1 = 0.f;
    int lane = tid & 63, wv = tid >> 6;
    for (int r = 0; r < 8; ++r) {
        int h = hc * 8 + r;
        float nb[9];
        #pragma unroll
        for (int dh = -1; dh <= 1; ++dh) {
            #pragma unroll
            for (int dw = -1; dw <= 1; ++dw) {
                int hh = h + dh, ww = wx + dw;
                nb[(dh + 1) * 3 + dw + 1] =
                    (hh >= 0 && hh < 512 && ww >= 0 && ww < 512) ? ip[hh * 512 + ww] : 0.f;
            }
        }
        float a0 = 0.f, a1 = 0.f;
        #pragma unroll
        for (int k = 0; k < 9; ++k) { a0 += w0[k] * nb[k]; a1 += w1[k] * nb[k]; }
        a0 = gelu_f(a0 * s0 + t0);
        a1 = gelu_f(a1 * s1 + tt1);
        ca0 += a0; ca1 += a1;
        #pragma unroll
        for (int off = 32; off > 0; off >>= 1) {
            a0 += __shfl_down(a0, off, 64);
            a1 += __shfl_down(a1, off, 64);
        }
        if (lane == 0) { lred[0][r][wv] = a0; lred[1][r][wv] = a1; }
    }
    colpart[(((size_t)b * 128 + o0) * 64 + hc) * 512 + wx] = ca0;
    colpart[(((size_t)b * 128 + o1) * 64 + hc) * 512 + wx] = ca1;
    __syncthreads();
    if (tid < 16) {
        int oo = tid >> 3, r = tid & 7;
        float s = 0.f;
        #pragma unroll
        for (int i = 0; i < 8; ++i) s += lred[oo][r][i];
        int och = oo == 0 ? o0 : o1;
        rowsum[((size_t)b * 128 + och) * 512 + hc * 8 + r] = s;
    }
}

// ---------------- v pooling: row/col sums of v ----------------
__global__ __launch_bounds__(512) void k_vpool(const float* __restrict__ v,
                                               float* __restrict__ rowsum,
                                               float* __restrict__ colpart) {
    __shared__ float lred[8][8];
    int tid = threadIdx.x;
    int blk = blockIdx.x;     // (b*128+c)*64+hc
    int hc = blk & 63;
    int bc = blk >> 6;
    const float* ip = v + (size_t)bc * PLANE;
    float ca = 0.f;
    int lane = tid & 63, wv = tid >> 6;
    for (int r = 0; r < 8; ++r) {
        float a = ip[(hc * 8 + r) * 512 + tid];
        ca += a;
        #pragma unroll
        for (int off = 32; off > 0; off >>= 1) a += __shfl_down(a, off, 64);
        if (lane == 0) lred[r][wv] = a;
    }
    colpart[((size_t)bc * 64 + hc) * 512 + tid] = ca;
    __syncthreads();
    if (tid < 8) {
        float s = 0.f;
        #pragma unroll
        for (int i = 0; i < 8; ++i) s += lred[tid][i];
        rowsum[(size_t)bc * 512 + hc * 8 + tid] = s;
    }
}

// ---------------- reduce col partials (64 chunks) ----------------
__global__ __launch_bounds__(256) void k_colreduce(const float* __restrict__ part,
                                                   float* __restrict__ out, int n) {
    int idx = blockIdx.x * 256 + threadIdx.x;
    if (idx >= n) return;
    int bc = idx >> 9, w = idx & 511;
    const float* pp = part + ((size_t)bc * 64) * 512 + w;
    float s = 0.f;
    #pragma unroll
    for (int p = 0; p < 64; ++p) s += pp[p * 512];
    out[idx] = s;
}

// ---------------- K6: axial attention (row & col), tiny ----------------
__global__ __launch_bounds__(256) void k_attn(const float* __restrict__ qrow,
                                              const float* __restrict__ krow,
                                              const float* __restrict__ vrow,
                                              const float* __restrict__ qcol,
                                              const float* __restrict__ kcol,
                                              const float* __restrict__ vcol,
                                              const float* __restrict__ perq,
                                              const float* __restrict__ perk,
                                              const float* __restrict__ pecq,
                                              const float* __restrict__ peck,
                                              float* __restrict__ arow,
                                              float* __restrict__ acol) {
    __shared__ float P[16][17];
    int blk = blockIdx.x;   // b*16 + head*2 + axis
    int axis = blk & 1;
    int head = (blk >> 1) & 7;
    int b = blk >> 4;
    const float* qs = axis ? qcol : qrow;
    const float* ks = axis ? kcol : krow;
    const float* vs = axis ? vcol : vrow;
    const float* peq = axis ? pecq : perq;
    const float* pek = axis ? peck : perk;
    float* out = axis ? acol : arow;
    int tid = threadIdx.x;
    int i = tid >> 4, j = tid & 15;
    int ci = head * 16 + i, cj = head * 16 + j;
    const float* qp = qs + ((size_t)b * 128 + ci) * 512;
    const float* kp = ks + ((size_t)b * 128 + cj) * 512;
    const float* qe = peq + ci * 512;
    const float* ke = pek + cj * 512;
    float s = 0.f;
    for (int n = 0; n < 512; ++n) {
        float qv = qp[n] * (1.f / 512.f) + qe[n];
        float kv = kp[n] * (1.f / 512.f) + ke[n];
        s += qv * kv;
    }
    s *= 0.0441941738241592203f;   // 1/sqrt(512)
    P[i][j] = s;
    __syncthreads();
    if (tid < 16) {
        float mx = -1e30f;
        #pragma unroll
        for (int jj = 0; jj < 16; ++jj) mx = fmaxf(mx, P[tid][jj]);
        float e[16];
        float sum = 0.f;
        #pragma unroll
        for (int jj = 0; jj < 16; ++jj) { e[jj] = expf(P[tid][jj] - mx); sum += e[jj]; }
        float inv = 1.f / sum;
        #pragma unroll
        for (int jj = 0; jj < 16; ++jj) P[tid][jj] = e[jj] * inv;
    }
    __syncthreads();
    for (int idx = tid; idx < 16 * 512; idx += 256) {
        int ii = idx >> 9, n = idx & 511;
        const float* vb = vs + ((size_t)b * 128 + head * 16) * 512 + n;
        float acc = 0.f;
        #pragma unroll
        for (int jj = 0; jj < 16; ++jj) acc += P[ii][jj] * vb[jj * 512] * (1.f / 512.f);
        out[((size_t)b * 128 + head * 16 + ii) * 512 + n] = acc;
    }
}

// ---------------- setup: shuffled pw weights -> bf16 ----------------
__global__ __launch_bounds__(256) void k_wsetup(const float* __restrict__ pww,
                                                unsigned short* __restrict__ wsh) {
    int tid = blockIdx.x * 256 + threadIdx.x;
    if (tid >= 64 * 320) return;
    int m = tid / 320, src = tid % 320;
    int o = (src % 5) * 64 + src / 5;     // shuffled-channel index fed by cat channel `src`
    wsh[m * 320 + src] = f2bf(pww[m * 320 + o]);
}

// ---------------- setup: attn fold map AW[b][c][col] ----------------
// AW = sum_dc (w0dc+w1dc+w2dc) * A(c, col+dc-1) * colvalid   (interior-h weights)
__global__ __launch_bounds__(256) void k_awsetup(const float* __restrict__ pdw,
                                                 const float* __restrict__ aprw,
                                                 const float* __restrict__ apcw,
                                                 const float* __restrict__ arow,
                                                 const float* __restrict__ acol,
                                                 float* __restrict__ aw) {
    int idx = blockIdx.x * 256 + threadIdx.x;   // 2*128*512
    if (idx >= 2 * 128 * 512) return;
    int col = idx & 511;
    int c   = (idx >> 9) & 127;
    int b   = idx >> 16;
    int src = 64 + c;
    int o = (src % 5) * 64 + src / 5;
    const float* wd = pdw + o * 9;
    float ws0 = wd[0] + wd[3] + wd[6];
    float ws1 = wd[1] + wd[4] + wd[7];
    float ws2 = wd[2] + wd[5] + wd[8];
    const float* ar = arow + ((size_t)b * 128 + c) * 512;
    const float* ac = acol + ((size_t)b * 128 + c) * 512;
    float apr = aprw[c], apc = apcw[c];
    float sum = ws1 * (apr * ar[col] + apc * ac[col]);
    if (col > 0)   sum += ws0 * (apr * ar[col - 1] + apc * ac[col - 1]);
    if (col < 511) sum += ws2 * (apr * ar[col + 1] + apc * ac[col + 1]);
    aw[idx] = sum;
}

// ---------------- K7 core: frag-direct conv + MFMA, no barriers ----------------
// Lane (cl,kg) of a wave owning px-tile [ww0..ww0+16) computes conv outputs for
// pixel ww = ww0+cl, channels kg*8+j of each 32-wide k-slice -> exactly the MFMA
// B-fragment. A-fragments reloaded from L1 per slice. Templated edge handling.
template<bool HE, bool WE>
__device__ __forceinline__ void proj_core(
    int h, int ww, int kg, int cl,
    const float* __restrict__ xb, const float* __restrict__ vbp,
    const float* __restrict__ arb, const float* __restrict__ acb,
    const float* __restrict__ aprw, const float* __restrict__ apcw,
    const float* __restrict__ awb, const float* dwl,
    const unsigned short* __restrict__ wsh, const float* __restrict__ pwb,
    float* __restrict__ outb)
{
    int hm = h - 1, hp = h + 1;
    float rv0 = 1.f, rv2 = 1.f, cv0 = 1.f, cv2 = 1.f;
    int ls = -1, rs = 1;
    if (HE) {
        if (h == 0)   { hm = 0;   rv0 = 0.f; }
        if (h == 511) { hp = 511; rv2 = 0.f; }
    }
    if (WE) {
        if (ww == 0)   { ls = 1;  cv0 = 0.f; }
        if (ww == 511) { rs = -1; cv2 = 0.f; }
    }
    f32x4 acc[4];
    #pragma unroll
    for (int mt = 0; mt < 4; ++mt) acc[mt] = (f32x4){0.f, 0.f, 0.f, 0.f};

    #pragma unroll
    for (int ks = 0; ks < 10; ++ks) {
        int ch0 = ks * 32 + kg * 8;
        const float* p;
        bool attn = false;
        if (ch0 < 64)        { p = xb + (size_t)ch0 * PLANE; }
        else if (ch0 < 192)  { p = vbp + (size_t)(ch0 - 64) * PLANE; attn = true; }
        else                 { p = vbp + (size_t)(ch0 - 192) * PLANE; }
        const float* awp = awb + (size_t)(ch0 - 64) * 512 + ww;
        const float* wl = dwl + ch0 * 12;
        float cvb[8];
        #pragma unroll
        for (int j = 0; j < 8; ++j) {
            const float* r0 = p + hm * 512 + ww;
            const float* r1 = p + h  * 512 + ww;
            const float* r2 = p + hp * 512 + ww;
            float w0 = wl[0], w1 = wl[1], w2 = wl[2];
            float w3 = wl[3], w4 = wl[4], w5 = wl[5];
            float w6 = wl[6], w7 = wl[7], w8 = wl[8], bia = wl[9];
            float A0, A1, A2, B0, B1, B2, C0, C1, C2;
            if (!HE && !WE) {
                A0 = r0[-1]; A1 = r0[0]; A2 = r0[1];
                B0 = r1[-1]; B1 = r1[0]; B2 = r1[1];
                C0 = r2[-1]; C1 = r2[0]; C2 = r2[1];
            } else {
                A0 = r0[ls] * cv0; A1 = r0[0]; A2 = r0[rs] * cv2;
                B0 = r1[ls] * cv0; B1 = r1[0]; B2 = r1[rs] * cv2;
                C0 = r2[ls] * cv0; C1 = r2[0]; C2 = r2[rs] * cv2;
            }
            float s0 = w0 * A0 + w1 * A1 + w2 * A2;
            float s1 = w3 * B0 + w4 * B1 + w5 * B2 + bia;
            float s2 = w6 * C0 + w7 * C1 + w8 * C2;
            float conv = HE ? (rv0 * s0 + s1 + rv2 * s2) : (s0 + s1 + s2);
            if (attn) {
                if (!HE) {
                    conv += awp[(size_t)j * 512];
                } else {
                    int c = ch0 - 64 + j;
                    float apr = aprw[c], apc = apcw[c];
                    const float* arpj = arb + (size_t)c * 512 + ww;
                    const float* acpj = acb + (size_t)c * 512 + ww;
                    float aa0 = (apr * arpj[ls] + apc * acpj[ls]) * cv0;
                    float aa1 =  apr * arpj[0]  + apc * acpj[0];
                    float aa2 = (apr * arpj[rs] + apc * acpj[rs]) * cv2;
                    float wd0 = rv0 * w0 + w3 + rv2 * w6;
                    float wd1 = rv0 * w1 + w4 + rv2 * w7;
                    float wd2 = rv0 * w2 + w5 + rv2 * w8;
                    conv += wd0 * aa0 + wd1 * aa1 + wd2 * aa2;
                }
            }
            cvb[j] = gelu_f(conv);
            p += PLANE;
            wl += 12;
        }
        union { bf16x8 v; unsigned u[4]; } bp;
        #pragma unroll
        for (int q = 0; q < 4; ++q) {
            unsigned r;
            asm("v_cvt_pk_bf16_f32 %0, %1, %2" : "=v"(r) : "v"(cvb[2*q]), "v"(cvb[2*q+1]));
            bp.u[q] = r;
        }
        const unsigned short* wp = wsh + (size_t)cl * 320 + ks * 32 + kg * 8;
        bf16x8 af[4];
        #pragma unroll
        for (int mt = 0; mt < 4; ++mt)
            af[mt] = *(const bf16x8*)(wp + mt * 16 * 320);
        #pragma unroll
        for (int mt = 0; mt < 4; ++mt)
            acc[mt] = __builtin_amdgcn_mfma_f32_16x16x32_bf16(af[mt], bp.v, acc[mt], 0, 0, 0);
    }
    // epilogue: D row = kg*4+r within m-tile, col = cl -> ww
    #pragma unroll
    for (int mt = 0; mt < 4; ++mt) {
        #pragma unroll
        for (int r = 0; r < 4; ++r) {
            int m = mt * 16 + kg * 4 + r;
            outb[(size_t)m * PLANE + h * 512 + ww] = gelu_f(acc[mt][r] + pwb[m]);
        }
    }
}

__global__ __launch_bounds__(256, 4) void k_proj3(
    const float* __restrict__ x, const float* __restrict__ v,
    const float* __restrict__ arow, const float* __restrict__ acol,
    const float* __restrict__ aprw, const float* __restrict__ apcw,
    const float* __restrict__ dww, const float* __restrict__ dwb,
    const unsigned short* __restrict__ wsh, const float* __restrict__ pwb,
    const float* __restrict__ aw, float* __restrict__ out)
{
    __shared__ float dwl[320 * 12];        // shuffled dw weights+bias, 16B-aligned rows
    int tid = threadIdx.x;
    for (int i = tid; i < 3200; i += 256) {
        int src = i / 10, k = i - src * 10;
        int o = (src % 5) * 64 + src / 5;
        dwl[src * 12 + k] = (k < 9) ? dww[o * 9 + k] : dwb[o];
    }
    __syncthreads();
    // XCD swizzle: contiguous h-chunks per XCD for L2 row reuse
    int flat = blockIdx.x;
    int nf = (flat & 7) * 1024 + (flat >> 3);
    int bx = nf & 7;
    int h  = (nf >> 3) & 511;
    int b  = nf >> 12;
    int lane = tid & 63, wva = tid >> 6;
    int cl = lane & 15, kg = lane >> 4;
    int ww = bx * 64 + wva * 16 + cl;
    const float* xb  = x + (size_t)b * 64 * PLANE;
    const float* vbp = v + (size_t)b * 128 * PLANE;
    const float* arb = arow + (size_t)b * 128 * 512;
    const float* acb = acol + (size_t)b * 128 * 512;
    const float* awb = aw + (size_t)b * 128 * 512;
    float* outb = out + (size_t)b * 64 * PLANE;
    bool HEr = (h == 0) || (h == 511);
    bool WEr = (bx == 0) || (bx == 7);
    if (!HEr && !WEr)
        proj_core<false,false>(h, ww, kg, cl, xb, vbp, arb, acb, aprw, apcw, awb, dwl, wsh, pwb, outb);
    else if (!HEr)
        proj_core<false,true >(h, ww, kg, cl, xb, vbp, arb, acb, aprw, apcw, awb, dwl, wsh, pwb, outb);
    else
        proj_core<true ,true >(h, ww, kg, cl, xb, vbp, arb, acb, aprw, apcw, awb, dwl, wsh, pwb, outb);
}

extern "C" void kernel_launch(void* const* d_in, const int* in_sizes, int n_in,
                              void* d_out, int out_size, void* d_ws, size_t ws_size,
                              hipStream_t stream) {
    const float* x    = (const float*)d_in[0];
    const float* sc   = (const float*)d_in[1];
    const float* lnw  = (const float*)d_in[2];
    const float* lnb  = (const float*)d_in[3];
    const float* ddw  = (const float*)d_in[4];
    const float* dbs  = (const float*)d_in[5];
    const float* dbt  = (const float*)d_in[6];
    const float* pw1  = (const float*)d_in[7];
    const float* pb1  = (const float*)d_in[8];
    const float* qdw  = (const float*)d_in[9];
    const float* qbs  = (const float*)d_in[10];
    const float* qbt  = (const float*)d_in[11];
    const float* kdw  = (const float*)d_in[12];
    const float* kbs  = (const float*)d_in[13];
    const float* kbt  = (const float*)d_in[14];
    const float* vpw  = (const float*)d_in[15];
    const float* vbs  = (const float*)d_in[16];
    const float* vbt  = (const float*)d_in[17];
    const float* pdw  = (const float*)d_in[18];
    const float* pdb  = (const float*)d_in[19];
    const float* ppw  = (const float*)d_in[20];
    const float* ppb  = (const float*)d_in[21];
    const float* perq = (const float*)d_in[22];
    const float* perk = (const float*)d_in[23];
    const float* pecq = (const float*)d_in[24];
    const float* peck = (const float*)d_in[25];
    const float* aprw = (const float*)d_in[26];
    const float* apcw = (const float*)d_in[27];

    // d_out doubles as scratch: sn (K1->K2), then k_in (K3->K4), then final out (K7).
    float* bufA = (float*)d_out;         // 33,554,432 floats
    float* ws   = (float*)d_ws;
    float* bufB = ws;                    // 33,554,432 floats: t1, later col partials
    float* bufV = ws + 33554432;         // 67,108,864 floats: v
    float* sm   = ws + 100663296;        // pooled vectors (1,048,576 floats)
    float* qrow = sm;
    float* krow = sm + 131072;
    float* vrow = sm + 262144;
    float* qcol = sm + 393216;
    float* kcol = sm + 524288;
    float* vcol = sm + 655360;
    float* arow = sm + 786432;
    float* acol = sm + 917504;
    unsigned short* wsh = (unsigned short*)(ws + 101711872);   // 20480 bf16 = 10240 floats
    float* aw   = ws + 101722112;        // 131,072 floats attn fold map
    float* qcp  = bufB;                  // col partials alias dead t1 buffer
    float* kcp  = bufB + 8388608;
    float* vcp  = bufB + 16777216;

    k_wsetup<<<80,    256, 0, stream>>>(ppw, wsh);
    k_ln   <<<4096,   128, 0, stream>>>(sc, lnw, lnb, bufA);
    k_dw64 <<<131072, 256, 0, stream>>>(bufA, ddw, dbs, dbt, bufB);
    k_pw_kv<<<2048,   256, 0, stream>>>(bufB, pw1, pb1, vpw, vbs, vbt, bufA, bufV);
    k_dwpool<<<8192,  512, 0, stream>>>(x,    qdw, qbs, qbt, qrow, qcp);
    k_dwpool<<<8192,  512, 0, stream>>>(bufA, kdw, kbs, kbt, krow, kcp);
    k_vpool<<<16384,  512, 0, stream>>>(bufV, vrow, vcp);
    k_colreduce<<<512, 256, 0, stream>>>(qcp, qcol, 131072);
    k_colreduce<<<512, 256, 0, stream>>>(kcp, kcol, 131072);
    k_colreduce<<<512, 256, 0, stream>>>(vcp, vcol, 131072);
    k_attn <<<32,     256, 0, stream>>>(qrow, krow, vrow, qcol, kcol, vcol,
                                        perq, perk, pecq, peck, arow, acol);
    k_awsetup<<<512,  256, 0, stream>>>(pdw, aprw, apcw, arow, acol, aw);
    k_proj3<<<8192,   256, 0, stream>>>(x, bufV, arow, acol, aprw, apcw,
                                        pdw, pdb, wsh, ppb, aw, (float*)d_out);
}

// Round 7
// 1510.799 us; speedup vs baseline: 1.7800x; 1.7800x over previous
//
#include <hip/hip_runtime.h>
#include <math.h>

#define PLANE (512*512)

typedef short bf16x8 __attribute__((ext_vector_type(8)));
typedef float f32x4 __attribute__((ext_vector_type(4)));

// fast GELU: 0.5*x*(1+erf(x/sqrt(2))), erf via Abramowitz-Stegun 7.1.26 (|err|<=1.5e-7)
__device__ __forceinline__ float gelu_f(float x) {
    float ax = fabsf(x) * 0.70710678118654752440f;   // z = |x|/sqrt(2)
    float t = __builtin_amdgcn_rcpf(1.0f + 0.3275911f * ax);
    float poly = t * (0.254829592f + t * (-0.284496736f + t * (1.421413741f
               + t * (-1.453152027f + t * 1.061405429f))));
    float e = __expf(-ax * ax);
    float er = 1.0f - poly * e;
    er = copysignf(er, x);
    return 0.5f * x * (1.0f + er);
}

__device__ __forceinline__ unsigned short f2bf(float f) {
    union { float f; unsigned u; } v; v.f = f;
    unsigned r = v.u + 0x7FFFu + ((v.u >> 16) & 1u);
    return (unsigned short)(r >> 16);
}

// ---------------- K1: LayerNorm over channels (64) ----------------
__global__ __launch_bounds__(128) void k_ln(const float* __restrict__ sc,
                                            const float* __restrict__ lnw,
                                            const float* __restrict__ lnb,
                                            float* __restrict__ sn) {
    __shared__ float tile[64 * 128];
    int tid = threadIdx.x;
    int p = blockIdx.x * 128 + tid;       // 0 .. 524287
    int b = p >> 18;
    int hw = p & (PLANE - 1);
    const float* src = sc + (size_t)b * 64 * PLANE + hw;
    float sum = 0.f, sq = 0.f;
    #pragma unroll 8
    for (int c = 0; c < 64; ++c) {
        float v = src[(size_t)c * PLANE];
        tile[c * 128 + tid] = v;
        sum += v; sq += v * v;
    }
    float mu = sum * (1.0f / 64.0f);
    float var = sq * (1.0f / 64.0f) - mu * mu;
    float rstd = rsqrtf(var + 1e-5f);
    float* dst = sn + (size_t)b * 64 * PLANE + hw;
    #pragma unroll 8
    for (int c = 0; c < 64; ++c) {
        float v = tile[c * 128 + tid];
        dst[(size_t)c * PLANE] = (v - mu) * rstd * lnw[c] + lnb[c];
    }
}

// ---------------- K2: depthwise 3x3 (64ch) + BN + GELU ----------------
__global__ __launch_bounds__(256) void k_dw64(const float* __restrict__ in,
                                              const float* __restrict__ wt,
                                              const float* __restrict__ bns,
                                              const float* __restrict__ bnt,
                                              float* __restrict__ out) {
    int idx = blockIdx.x * 256 + threadIdx.x;   // over 2*64*PLANE
    int w = idx & 511;
    int h = (idx >> 9) & 511;
    int bc = idx >> 18;
    int c = bc & 63;
    const float* ip = in + (size_t)bc * PLANE;
    const float* wp = wt + c * 9;
    float acc = 0.f;
    #pragma unroll
    for (int dh = -1; dh <= 1; ++dh) {
        int hh = h + dh; if (hh < 0 || hh > 511) continue;
        #pragma unroll
        for (int dw = -1; dw <= 1; ++dw) {
            int ww = w + dw; if (ww < 0 || ww > 511) continue;
            acc += wp[(dh + 1) * 3 + (dw + 1)] * ip[hh * 512 + ww];
        }
    }
    out[idx] = gelu_f(acc * bns[c] + bnt[c]);
}

// ---------------- K3: per-pixel pw 64->128 (+gelu) -> split; v = bn(pw 64->128) ----------------
__global__ __launch_bounds__(256) void k_pw_kv(const float* __restrict__ t1,
                                               const float* __restrict__ W1,
                                               const float* __restrict__ b1,
                                               const float* __restrict__ W2,
                                               const float* __restrict__ vbs,
                                               const float* __restrict__ vbt,
                                               float* __restrict__ k_in,
                                               float* __restrict__ v) {
    __shared__ float Wl[128 * 64];
    __shared__ float pb[128], ps[128], pt[128];
    int tid = threadIdx.x;
    int p = blockIdx.x * 256 + tid;
    int b = p >> 18;
    int hw = p & (PLANE - 1);
    for (int i = tid; i < 8192; i += 256) Wl[i] = W1[i];
    if (tid < 128) { pb[tid] = b1[tid]; ps[tid] = vbs[tid]; pt[tid] = vbt[tid]; }
    float t1r[64];
    const float* tp = t1 + (size_t)b * 64 * PLANE + hw;
    #pragma unroll
    for (int i = 0; i < 64; ++i) t1r[i] = tp[(size_t)i * PLANE];
    __syncthreads();
    float vin[64];
    float* kp = k_in + (size_t)b * 64 * PLANE + hw;
    for (int o = 0; o < 128; ++o) {
        float acc = pb[o];
        const float4* wr = (const float4*)&Wl[o * 64];
        #pragma unroll
        for (int i4 = 0; i4 < 16; ++i4) {
            float4 wv = wr[i4];
            acc += wv.x * t1r[i4 * 4 + 0] + wv.y * t1r[i4 * 4 + 1]
                 + wv.z * t1r[i4 * 4 + 2] + wv.w * t1r[i4 * 4 + 3];
        }
        float g = gelu_f(acc);
        if (o < 64) kp[(size_t)o * PLANE] = g;
        else        vin[o - 64] = g;
    }
    __syncthreads();
    for (int i = tid; i < 8192; i += 256) Wl[i] = W2[i];
    __syncthreads();
    float* vp = v + (size_t)b * 128 * PLANE + hw;
    for (int o = 0; o < 128; ++o) {
        float acc = 0.f;
        const float4* wr = (const float4*)&Wl[o * 64];
        #pragma unroll
        for (int i4 = 0; i4 < 16; ++i4) {
            float4 wv = wr[i4];
            acc += wv.x * vin[i4 * 4 + 0] + wv.y * vin[i4 * 4 + 1]
                 + wv.z * vin[i4 * 4 + 2] + wv.w * vin[i4 * 4 + 3];
        }
        vp[(size_t)o * PLANE] = acc * ps[o] + pt[o];
    }
}

// ---------------- K4/K5: grouped dw 3x3 (64->128) + BN + GELU, emit row/col pooled sums only ----------------
__global__ __launch_bounds__(512) void k_dwpool(const float* __restrict__ in,
                                                const float* __restrict__ wt,
                                                const float* __restrict__ bns,
                                                const float* __restrict__ bnt,
                                                float* __restrict__ rowsum,   // (B,128,512)
                                                float* __restrict__ colpart) { // (B,128,64,512)
    __shared__ float lred[2][8][8];
    int tid = threadIdx.x;
    int blk = blockIdx.x;            // (b*64+g)*64+hc
    int hc = blk & 63;
    int g  = (blk >> 6) & 63;
    int b  = blk >> 12;
    int o0 = 2 * g, o1 = 2 * g + 1;
    const float* ip = in + ((size_t)b * 64 + g) * PLANE;
    float w0[9], w1[9];
    #pragma unroll
    for (int k = 0; k < 9; ++k) { w0[k] = wt[o0 * 9 + k]; w1[k] = wt[o1 * 9 + k]; }
    float s0 = bns[o0], t0 = bnt[o0], s1 = bns[o1], tt1 = bnt[o1];
    int wx = tid;
    float ca0 = 0.f, ca1 = 0.f;
    int lane = tid & 63, wv = tid >> 6;
    for (int r = 0; r < 8; ++r) {
        int h = hc * 8 + r;
        float nb[9];
        #pragma unroll
        for (int dh = -1; dh <= 1; ++dh) {
            #pragma unroll
            for (int dw = -1; dw <= 1; ++dw) {
                int hh = h + dh, ww = wx + dw;
                nb[(dh + 1) * 3 + dw + 1] =
                    (hh >= 0 && hh < 512 && ww >= 0 && ww < 512) ? ip[hh * 512 + ww] : 0.f;
            }
        }
        float a0 = 0.f, a1 = 0.f;
        #pragma unroll
        for (int k = 0; k < 9; ++k) { a0 += w0[k] * nb[k]; a1 += w1[k] * nb[k]; }
        a0 = gelu_f(a0 * s0 + t0);
        a1 = gelu_f(a1 * s1 + tt1);
        ca0 += a0; ca1 += a1;
        #pragma unroll
        for (int off = 32; off > 0; off >>= 1) {
            a0 += __shfl_down(a0, off, 64);
            a1 += __shfl_down(a1, off, 64);
        }
        if (lane == 0) { lred[0][r][wv] = a0; lred[1][r][wv] = a1; }
    }
    colpart[(((size_t)b * 128 + o0) * 64 + hc) * 512 + wx] = ca0;
    colpart[(((size_t)b * 128 + o1) * 64 + hc) * 512 + wx] = ca1;
    __syncthreads();
    if (tid < 16) {
        int oo = tid >> 3, r = tid & 7;
        float s = 0.f;
        #pragma unroll
        for (int i = 0; i < 8; ++i) s += lred[oo][r][i];
        int och = oo == 0 ? o0 : o1;
        rowsum[((size_t)b * 128 + och) * 512 + hc * 8 + r] = s;
    }
}

// ---------------- v pooling: row/col sums of v ----------------
__global__ __launch_bounds__(512) void k_vpool(const float* __restrict__ v,
                                               float* __restrict__ rowsum,
                                               float* __restrict__ colpart) {
    __shared__ float lred[8][8];
    int tid = threadIdx.x;
    int blk = blockIdx.x;     // (b*128+c)*64+hc
    int hc = blk & 63;
    int bc = blk >> 6;
    const float* ip = v + (size_t)bc * PLANE;
    float ca = 0.f;
    int lane = tid & 63, wv = tid >> 6;
    for (int r = 0; r < 8; ++r) {
        float a = ip[(hc * 8 + r) * 512 + tid];
        ca += a;
        #pragma unroll
        for (int off = 32; off > 0; off >>= 1) a += __shfl_down(a, off, 64);
        if (lane == 0) lred[r][wv] = a;
    }
    colpart[((size_t)bc * 64 + hc) * 512 + tid] = ca;
    __syncthreads();
    if (tid < 8) {
        float s = 0.f;
        #pragma unroll
        for (int i = 0; i < 8; ++i) s += lred[tid][i];
        rowsum[(size_t)bc * 512 + hc * 8 + tid] = s;
    }
}

// ---------------- reduce col partials (64 chunks) ----------------
__global__ __launch_bounds__(256) void k_colreduce(const float* __restrict__ part,
                                                   float* __restrict__ out, int n) {
    int idx = blockIdx.x * 256 + threadIdx.x;
    if (idx >= n) return;
    int bc = idx >> 9, w = idx & 511;
    const float* pp = part + ((size_t)bc * 64) * 512 + w;
    float s = 0.f;
    #pragma unroll
    for (int p = 0; p < 64; ++p) s += pp[p * 512];
    out[idx] = s;
}

// ---------------- K6: axial attention (row & col), tiny ----------------
__global__ __launch_bounds__(256) void k_attn(const float* __restrict__ qrow,
                                              const float* __restrict__ krow,
                                              const float* __restrict__ vrow,
                                              const float* __restrict__ qcol,
                                              const float* __restrict__ kcol,
                                              const float* __restrict__ vcol,
                                              const float* __restrict__ perq,
                                              const float* __restrict__ perk,
                                              const float* __restrict__ pecq,
                                              const float* __restrict__ peck,
                                              float* __restrict__ arow,
                                              float* __restrict__ acol) {
    __shared__ float P[16][17];
    int blk = blockIdx.x;   // b*16 + head*2 + axis
    int axis = blk & 1;
    int head = (blk >> 1) & 7;
    int b = blk >> 4;
    const float* qs = axis ? qcol : qrow;
    const float* ks = axis ? kcol : krow;
    const float* vs = axis ? vcol : vrow;
    const float* peq = axis ? pecq : perq;
    const float* pek = axis ? peck : perk;
    float* out = axis ? acol : arow;
    int tid = threadIdx.x;
    int i = tid >> 4, j = tid & 15;
    int ci = head * 16 + i, cj = head * 16 + j;
    const float* qp = qs + ((size_t)b * 128 + ci) * 512;
    const float* kp = ks + ((size_t)b * 128 + cj) * 512;
    const float* qe = peq + ci * 512;
    const float* ke = pek + cj * 512;
    float s = 0.f;
    for (int n = 0; n < 512; ++n) {
        float qv = qp[n] * (1.f / 512.f) + qe[n];
        float kv = kp[n] * (1.f / 512.f) + ke[n];
        s += qv * kv;
    }
    s *= 0.0441941738241592203f;   // 1/sqrt(512)
    P[i][j] = s;
    __syncthreads();
    if (tid < 16) {
        float mx = -1e30f;
        #pragma unroll
        for (int jj = 0; jj < 16; ++jj) mx = fmaxf(mx, P[tid][jj]);
        float e[16];
        float sum = 0.f;
        #pragma unroll
        for (int jj = 0; jj < 16; ++jj) { e[jj] = expf(P[tid][jj] - mx); sum += e[jj]; }
        float inv = 1.f / sum;
        #pragma unroll
        for (int jj = 0; jj < 16; ++jj) P[tid][jj] = e[jj] * inv;
    }
    __syncthreads();
    for (int idx = tid; idx < 16 * 512; idx += 256) {
        int ii = idx >> 9, n = idx & 511;
        const float* vb = vs + ((size_t)b * 128 + head * 16) * 512 + n;
        float acc = 0.f;
        #pragma unroll
        for (int jj = 0; jj < 16; ++jj) acc += P[ii][jj] * vb[jj * 512] * (1.f / 512.f);
        out[((size_t)b * 128 + head * 16 + ii) * 512 + n] = acc;
    }
}

// ---------------- setup: shuffled pw weights -> bf16 ----------------
__global__ __launch_bounds__(256) void k_wsetup(const float* __restrict__ pww,
                                                unsigned short* __restrict__ wsh) {
    int tid = blockIdx.x * 256 + threadIdx.x;
    if (tid >= 64 * 320) return;
    int m = tid / 320, src = tid % 320;
    int o = (src % 5) * 64 + src / 5;     // shuffled-channel index fed by cat channel `src`
    wsh[m * 320 + src] = f2bf(pww[m * 320 + o]);
}

// ---------------- setup: attn fold map AW[b][c][col] ----------------
// AW = sum_dc (w0dc+w1dc+w2dc) * A(c, col+dc-1) * colvalid   (interior-h weights)
__global__ __launch_bounds__(256) void k_awsetup(const float* __restrict__ pdw,
                                                 const float* __restrict__ aprw,
                                                 const float* __restrict__ apcw,
                                                 const float* __restrict__ arow,
                                                 const float* __restrict__ acol,
                                                 float* __restrict__ aw) {
    int idx = blockIdx.x * 256 + threadIdx.x;   // 2*128*512
    if (idx >= 2 * 128 * 512) return;
    int col = idx & 511;
    int c   = (idx >> 9) & 127;
    int b   = idx >> 16;
    int src = 64 + c;
    int o = (src % 5) * 64 + src / 5;
    const float* wd = pdw + o * 9;
    float ws0 = wd[0] + wd[3] + wd[6];
    float ws1 = wd[1] + wd[4] + wd[7];
    float ws2 = wd[2] + wd[5] + wd[8];
    const float* ar = arow + ((size_t)b * 128 + c) * 512;
    const float* ac = acol + ((size_t)b * 128 + c) * 512;
    float apr = aprw[c], apc = apcw[c];
    float sum = ws1 * (apr * ar[col] + apc * ac[col]);
    if (col > 0)   sum += ws0 * (apr * ar[col - 1] + apc * ac[col - 1]);
    if (col < 511) sum += ws2 * (apr * ar[col + 1] + apc * ac[col + 1]);
    aw[idx] = sum;
}

// ---------------- K7 v4: strip-of-4 frag-direct conv + MFMA + LDS-coalesced epilogue ----
// Rolling-register taps (6 rows per 4 output rows), fused attn/plain v convs
// (one tap load, two weight sets), LDS-transpose epilogue for 256B-contiguous stores.

// dual conv: 4 strip rows from rolling taps, two weight sets sharing taps
template<bool HE, bool WE>
__device__ __forceinline__ void conv2x(const float* __restrict__ p,
    const float* wlA, const float* wlP,
    const int* hrow, const float* rv, int ls, int rs, float cv0, float cv2,
    float outA[4], float outP[4])
{
    float a0,a1,a2, b0,b1,b2, c0,c1,c2;
    const float* q = p + hrow[0]*512;
    if (WE) { a0=q[ls]*cv0; a1=q[0]; a2=q[rs]*cv2; } else { a0=q[-1]; a1=q[0]; a2=q[1]; }
    q = p + hrow[1]*512;
    if (WE) { b0=q[ls]*cv0; b1=q[0]; b2=q[rs]*cv2; } else { b0=q[-1]; b1=q[0]; b2=q[1]; }
    q = p + hrow[2]*512;
    if (WE) { c0=q[ls]*cv0; c1=q[0]; c2=q[rs]*cv2; } else { c0=q[-1]; c1=q[0]; c2=q[1]; }
    #pragma unroll
    for (int hs = 0; hs < 4; ++hs) {
        float sA0 = wlA[0]*a0 + wlA[1]*a1 + wlA[2]*a2;
        float sA1 = wlA[3]*b0 + wlA[4]*b1 + wlA[5]*b2;
        float sA2 = wlA[6]*c0 + wlA[7]*c1 + wlA[8]*c2;
        float sP0 = wlP[0]*a0 + wlP[1]*a1 + wlP[2]*a2;
        float sP1 = wlP[3]*b0 + wlP[4]*b1 + wlP[5]*b2;
        float sP2 = wlP[6]*c0 + wlP[7]*c1 + wlP[8]*c2;
        if (HE) {
            outA[hs] = rv[hs]*sA0 + sA1 + rv[hs+2]*sA2 + wlA[9];
            outP[hs] = rv[hs]*sP0 + sP1 + rv[hs+2]*sP2 + wlP[9];
        } else {
            outA[hs] = sA0 + sA1 + sA2 + wlA[9];
            outP[hs] = sP0 + sP1 + sP2 + wlP[9];
        }
        if (hs < 3) {
            a0=b0; a1=b1; a2=b2; b0=c0; b1=c1; b2=c2;
            q = p + hrow[hs+3]*512;
            if (WE) { c0=q[ls]*cv0; c1=q[0]; c2=q[rs]*cv2; } else { c0=q[-1]; c1=q[0]; c2=q[1]; }
        }
    }
}

template<bool HE, bool WE>
__device__ __forceinline__ void conv1x(const float* __restrict__ p,
    const float* wl,
    const int* hrow, const float* rv, int ls, int rs, float cv0, float cv2,
    float out[4])
{
    float a0,a1,a2, b0,b1,b2, c0,c1,c2;
    const float* q = p + hrow[0]*512;
    if (WE) { a0=q[ls]*cv0; a1=q[0]; a2=q[rs]*cv2; } else { a0=q[-1]; a1=q[0]; a2=q[1]; }
    q = p + hrow[1]*512;
    if (WE) { b0=q[ls]*cv0; b1=q[0]; b2=q[rs]*cv2; } else { b0=q[-1]; b1=q[0]; b2=q[1]; }
    q = p + hrow[2]*512;
    if (WE) { c0=q[ls]*cv0; c1=q[0]; c2=q[rs]*cv2; } else { c0=q[-1]; c1=q[0]; c2=q[1]; }
    #pragma unroll
    for (int hs = 0; hs < 4; ++hs) {
        float s0 = wl[0]*a0 + wl[1]*a1 + wl[2]*a2;
        float s1 = wl[3]*b0 + wl[4]*b1 + wl[5]*b2;
        float s2 = wl[6]*c0 + wl[7]*c1 + wl[8]*c2;
        out[hs] = (HE ? (rv[hs]*s0 + s1 + rv[hs+2]*s2) : (s0 + s1 + s2)) + wl[9];
        if (hs < 3) {
            a0=b0; a1=b1; a2=b2; b0=c0; b1=c1; b2=c2;
            q = p + hrow[hs+3]*512;
            if (WE) { c0=q[ls]*cv0; c1=q[0]; c2=q[rs]*cv2; } else { c0=q[-1]; c1=q[0]; c2=q[1]; }
        }
    }
}

template<bool HE, bool WE>
__device__ __forceinline__ void proj4_core(
    int h0, int wwbase, float* epi, const float* dwl,
    const float* __restrict__ xb, const float* __restrict__ vbp,
    const float* __restrict__ arb, const float* __restrict__ acb,
    const float* __restrict__ aprw, const float* __restrict__ apcw,
    const float* __restrict__ awb,
    const unsigned short* __restrict__ wsh, const float* __restrict__ pwb,
    float* __restrict__ outb)
{
    int tid = threadIdx.x;
    int lane = tid & 63, wva = tid >> 6;
    int cl = lane & 15, kg = lane >> 4;
    int ww = wwbase + wva * 16 + cl;

    int hrow[6]; float rv[6];
    #pragma unroll
    for (int i = 0; i < 6; ++i) {
        int r = h0 - 1 + i;
        float va = 1.f;
        if (HE) { if (r < 0) { r = 0; va = 0.f; } if (r > 511) { r = 511; va = 0.f; } }
        hrow[i] = r; rv[i] = va;
    }
    int ls = -1, rs = 1; float cv0 = 1.f, cv2 = 1.f;
    if (WE) {
        if (ww == 0)   { ls = 1;  cv0 = 0.f; }
        if (ww == 511) { rs = -1; cv2 = 0.f; }
    }

    f32x4 acc[4][4];
    #pragma unroll
    for (int hs = 0; hs < 4; ++hs)
        #pragma unroll
        for (int mt = 0; mt < 4; ++mt)
            acc[hs][mt] = (f32x4){0.f, 0.f, 0.f, 0.f};

    // ---- x slices (ks 0,1) ----
    #pragma unroll
    for (int ks = 0; ks < 2; ++ks) {
        unsigned bp[4][4];
        #pragma unroll
        for (int jp = 0; jp < 4; ++jp) {
            float cj0[4], cj1[4];
            int ch = ks * 32 + kg * 8 + jp * 2;
            conv1x<HE,WE>(xb + (size_t)ch * PLANE + ww, dwl + ch * 12,
                          hrow, rv, ls, rs, cv0, cv2, cj0);
            conv1x<HE,WE>(xb + (size_t)(ch+1) * PLANE + ww, dwl + (ch+1) * 12,
                          hrow, rv, ls, rs, cv0, cv2, cj1);
            #pragma unroll
            for (int hs = 0; hs < 4; ++hs) {
                float g0 = gelu_f(cj0[hs]), g1 = gelu_f(cj1[hs]);
                unsigned r;
                asm("v_cvt_pk_bf16_f32 %0,%1,%2" : "=v"(r) : "v"(g0), "v"(g1));
                bp[hs][jp] = r;
            }
        }
        #pragma unroll
        for (int mt = 0; mt < 4; ++mt) {
            bf16x8 af = *(const bf16x8*)(wsh + (size_t)(mt * 16 + cl) * 320 + ks * 32 + kg * 8);
            #pragma unroll
            for (int hs = 0; hs < 4; ++hs) {
                union { unsigned u[4]; bf16x8 v; } bb;
                bb.u[0] = bp[hs][0]; bb.u[1] = bp[hs][1]; bb.u[2] = bp[hs][2]; bb.u[3] = bp[hs][3];
                acc[hs][mt] = __builtin_amdgcn_mfma_f32_16x16x32_bf16(af, bb.v, acc[hs][mt], 0, 0, 0);
            }
        }
    }

    // ---- v slices: fused attn (slice 2+vks) + plain (slice 6+vks) ----
    #pragma unroll
    for (int vks = 0; vks < 4; ++vks) {
        unsigned bpA[4][4], bpP[4][4];
        #pragma unroll
        for (int jp = 0; jp < 4; ++jp) {
            float cA[2][4], cP[2][4];
            #pragma unroll
            for (int e = 0; e < 2; ++e) {
                int c = vks * 32 + kg * 8 + jp * 2 + e;
                const float* wlA = dwl + (64 + c) * 12;
                conv2x<HE,WE>(vbp + (size_t)c * PLANE + ww, wlA, dwl + (192 + c) * 12,
                              hrow, rv, ls, rs, cv0, cv2, cA[e], cP[e]);
                float awv = awb[(size_t)c * 512 + ww];
                #pragma unroll
                for (int hs = 0; hs < 4; ++hs) {
                    if (!HE) {
                        cA[e][hs] += awv;
                    } else {
                        if (rv[hs] + rv[hs + 2] == 2.f) {
                            cA[e][hs] += awv;
                        } else {
                            const float* arp = arb + (size_t)c * 512 + ww;
                            const float* acp = acb + (size_t)c * 512 + ww;
                            float apr = aprw[c], apc = apcw[c];
                            float aa0 = (apr * arp[ls] + apc * acp[ls]) * cv0;
                            float aa1 =  apr * arp[0]  + apc * acp[0];
                            float aa2 = (apr * arp[rs] + apc * acp[rs]) * cv2;
                            float wd0 = rv[hs]*wlA[0] + wlA[3] + rv[hs+2]*wlA[6];
                            float wd1 = rv[hs]*wlA[1] + wlA[4] + rv[hs+2]*wlA[7];
                            float wd2 = rv[hs]*wlA[2] + wlA[5] + rv[hs+2]*wlA[8];
                            cA[e][hs] += wd0*aa0 + wd1*aa1 + wd2*aa2;
                        }
                    }
                }
            }
            #pragma unroll
            for (int hs = 0; hs < 4; ++hs) {
                float gA0 = gelu_f(cA[0][hs]), gA1 = gelu_f(cA[1][hs]);
                float gP0 = gelu_f(cP[0][hs]), gP1 = gelu_f(cP[1][hs]);
                unsigned ra, rp;
                asm("v_cvt_pk_bf16_f32 %0,%1,%2" : "=v"(ra) : "v"(gA0), "v"(gA1));
                asm("v_cvt_pk_bf16_f32 %0,%1,%2" : "=v"(rp) : "v"(gP0), "v"(gP1));
                bpA[hs][jp] = ra; bpP[hs][jp] = rp;
            }
        }
        #pragma unroll
        for (int mt = 0; mt < 4; ++mt) {
            bf16x8 afA = *(const bf16x8*)(wsh + (size_t)(mt * 16 + cl) * 320 + (2 + vks) * 32 + kg * 8);
            #pragma unroll
            for (int hs = 0; hs < 4; ++hs) {
                union { unsigned u[4]; bf16x8 v; } bb;
                bb.u[0] = bpA[hs][0]; bb.u[1] = bpA[hs][1]; bb.u[2] = bpA[hs][2]; bb.u[3] = bpA[hs][3];
                acc[hs][mt] = __builtin_amdgcn_mfma_f32_16x16x32_bf16(afA, bb.v, acc[hs][mt], 0, 0, 0);
            }
            bf16x8 afP = *(const bf16x8*)(wsh + (size_t)(mt * 16 + cl) * 320 + (6 + vks) * 32 + kg * 8);
            #pragma unroll
            for (int hs = 0; hs < 4; ++hs) {
                union { unsigned u[4]; bf16x8 v; } bb;
                bb.u[0] = bpP[hs][0]; bb.u[1] = bpP[hs][1]; bb.u[2] = bpP[hs][2]; bb.u[3] = bpP[hs][3];
                acc[hs][mt] = __builtin_amdgcn_mfma_f32_16x16x32_bf16(afP, bb.v, acc[hs][mt], 0, 0, 0);
            }
        }
    }

    // ---- epilogue: LDS transpose -> 256B-contiguous float4 stores ----
    #pragma unroll
    for (int hs = 0; hs < 4; ++hs) {
        __syncthreads();
        #pragma unroll
        for (int mt = 0; mt < 4; ++mt)
            #pragma unroll
            for (int r = 0; r < 4; ++r) {
                int m = mt * 16 + kg * 4 + r;
                epi[m * 68 + wva * 16 + cl] = gelu_f(acc[hs][mt][r] + pwb[m]);
            }
        __syncthreads();
        #pragma unroll
        for (int k = 0; k < 4; ++k) {
            int m = wva * 16 + k * 4 + kg;
            float4 vv = *(const float4*)&epi[m * 68 + cl * 4];
            *(float4*)&outb[(size_t)m * PLANE + (size_t)(h0 + hs) * 512 + wwbase + cl * 4] = vv;
        }
    }
}

__global__ __launch_bounds__(256, 3) void k_proj4(
    const float* __restrict__ x, const float* __restrict__ v,
    const float* __restrict__ arow, const float* __restrict__ acol,
    const float* __restrict__ aprw, const float* __restrict__ apcw,
    const float* __restrict__ dww, const float* __restrict__ dwb,
    const unsigned short* __restrict__ wsh, const float* __restrict__ pwb,
    const float* __restrict__ aw, float* __restrict__ out)
{
    __shared__ float dwl[320 * 12];   // 15,360 B
    __shared__ float epi[64 * 68];    // 17,408 B
    int tid = threadIdx.x;
    for (int i = tid; i < 3200; i += 256) {
        int src = i / 10, k = i - src * 10;
        int o = (src % 5) * 64 + src / 5;
        dwl[src * 12 + k] = (k < 9) ? dww[o * 9 + k] : dwb[o];
    }
    __syncthreads();
    // XCD swizzle: contiguous strip chunks per XCD
    int flat = blockIdx.x;                 // 0..2047
    int nf = (flat & 7) * 256 + (flat >> 3);
    int bx = nf & 7;
    int s  = (nf >> 3) & 127;
    int b  = nf >> 10;
    int h0 = s * 4, wwbase = bx * 64;
    const float* xb  = x + (size_t)b * 64 * PLANE;
    const float* vbp = v + (size_t)b * 128 * PLANE;
    const float* arb = arow + (size_t)b * 128 * 512;
    const float* acb = acol + (size_t)b * 128 * 512;
    const float* awb = aw + (size_t)b * 128 * 512;
    float* outb = out + (size_t)b * 64 * PLANE;
    bool HEr = (s == 0) || (s == 127);
    bool WEr = (bx == 0) || (bx == 7);
    if (!HEr && !WEr)
        proj4_core<false,false>(h0, wwbase, epi, dwl, xb, vbp, arb, acb, aprw, apcw, awb, wsh, pwb, outb);
    else if (!HEr)
        proj4_core<false,true >(h0, wwbase, epi, dwl, xb, vbp, arb, acb, aprw, apcw, awb, wsh, pwb, outb);
    else
        proj4_core<true ,true >(h0, wwbase, epi, dwl, xb, vbp, arb, acb, aprw, apcw, awb, wsh, pwb, outb);
}

extern "C" void kernel_launch(void* const* d_in, const int* in_sizes, int n_in,
                              void* d_out, int out_size, void* d_ws, size_t ws_size,
                              hipStream_t stream) {
    const float* x    = (const float*)d_in[0];
    const float* sc   = (const float*)d_in[1];
    const float* lnw  = (const float*)d_in[2];
    const float* lnb  = (const float*)d_in[3];
    const float* ddw  = (const float*)d_in[4];
    const float* dbs  = (const float*)d_in[5];
    const float* dbt  = (const float*)d_in[6];
    const float* pw1  = (const float*)d_in[7];
    const float* pb1  = (const float*)d_in[8];
    const float* qdw  = (const float*)d_in[9];
    const float* qbs  = (const float*)d_in[10];
    const float* qbt  = (const float*)d_in[11];
    const float* kdw  = (const float*)d_in[12];
    const float* kbs  = (const float*)d_in[13];
    const float* kbt  = (const float*)d_in[14];
    const float* vpw  = (const float*)d_in[15];
    const float* vbs  = (const float*)d_in[16];
    const float* vbt  = (const float*)d_in[17];
    const float* pdw  = (const float*)d_in[18];
    const float* pdb  = (const float*)d_in[19];
    const float* ppw  = (const float*)d_in[20];
    const float* ppb  = (const float*)d_in[21];
    const float* perq = (const float*)d_in[22];
    const float* perk = (const float*)d_in[23];
    const float* pecq = (const float*)d_in[24];
    const float* peck = (const float*)d_in[25];
    const float* aprw = (const float*)d_in[26];
    const float* apcw = (const float*)d_in[27];

    // d_out doubles as scratch: sn (K1->K2), then k_in (K3->K4), then final out (K7).
    float* bufA = (float*)d_out;         // 33,554,432 floats
    float* ws   = (float*)d_ws;
    float* bufB = ws;                    // 33,554,432 floats: t1, later col partials
    float* bufV = ws + 33554432;         // 67,108,864 floats: v
    float* sm   = ws + 100663296;        // pooled vectors (1,048,576 floats)
    float* qrow = sm;
    float* krow = sm + 131072;
    float* vrow = sm + 262144;
    float* qcol = sm + 393216;
    float* kcol = sm + 524288;
    float* vcol = sm + 655360;
    float* arow = sm + 786432;
    float* acol = sm + 917504;
    unsigned short* wsh = (unsigned short*)(ws + 101711872);   // 20480 bf16 = 10240 floats
    float* aw   = ws + 101722112;        // 131,072 floats attn fold map
    float* qcp  = bufB;                  // col partials alias dead t1 buffer
    float* kcp  = bufB + 8388608;
    float* vcp  = bufB + 16777216;

    k_wsetup<<<80,    256, 0, stream>>>(ppw, wsh);
    k_ln   <<<4096,   128, 0, stream>>>(sc, lnw, lnb, bufA);
    k_dw64 <<<131072, 256, 0, stream>>>(bufA, ddw, dbs, dbt, bufB);
    k_pw_kv<<<2048,   256, 0, stream>>>(bufB, pw1, pb1, vpw, vbs, vbt, bufA, bufV);
    k_dwpool<<<8192,  512, 0, stream>>>(x,    qdw, qbs, qbt, qrow, qcp);
    k_dwpool<<<8192,  512, 0, stream>>>(bufA, kdw, kbs, kbt, krow, kcp);
    k_vpool<<<16384,  512, 0, stream>>>(bufV, vrow, vcp);
    k_colreduce<<<512, 256, 0, stream>>>(qcp, qcol, 131072);
    k_colreduce<<<512, 256, 0, stream>>>(kcp, kcol, 131072);
    k_colreduce<<<512, 256, 0, stream>>>(vcp, vcol, 131072);
    k_attn <<<32,     256, 0, stream>>>(qrow, krow, vrow, qcol, kcol, vcol,
                                        perq, perk, pecq, peck, arow, acol);
    k_awsetup<<<512,  256, 0, stream>>>(pdw, aprw, apcw, arow, acol, aw);
    k_proj4<<<2048,   256, 0, stream>>>(x, bufV, arow, acol, aprw, apcw,
                                        pdw, pdb, wsh, ppb, aw, (float*)d_out);
}

// Round 8
// 1232.911 us; speedup vs baseline: 2.1812x; 1.2254x over previous
//
#include <hip/hip_runtime.h>
#include <math.h>

#define PLANE (512*512)

typedef short bf16x8 __attribute__((ext_vector_type(8)));
typedef float f32x4 __attribute__((ext_vector_type(4)));

// fast GELU: 0.5*x*(1+erf(x/sqrt(2))), erf via Abramowitz-Stegun 7.1.26 (|err|<=1.5e-7)
__device__ __forceinline__ float gelu_f(float x) {
    float ax = fabsf(x) * 0.70710678118654752440f;   // z = |x|/sqrt(2)
    float t = __builtin_amdgcn_rcpf(1.0f + 0.3275911f * ax);
    float poly = t * (0.254829592f + t * (-0.284496736f + t * (1.421413741f
               + t * (-1.453152027f + t * 1.061405429f))));
    float e = __expf(-ax * ax);
    float er = 1.0f - poly * e;
    er = copysignf(er, x);
    return 0.5f * x * (1.0f + er);
}

__device__ __forceinline__ unsigned short f2bf(float f) {
    union { float f; unsigned u; } v; v.f = f;
    unsigned r = v.u + 0x7FFFu + ((v.u >> 16) & 1u);
    return (unsigned short)(r >> 16);
}

// ---------------- K1: LayerNorm over channels (64) ----------------
__global__ __launch_bounds__(128) void k_ln(const float* __restrict__ sc,
                                            const float* __restrict__ lnw,
                                            const float* __restrict__ lnb,
                                            float* __restrict__ sn) {
    __shared__ float tile[64 * 128];
    int tid = threadIdx.x;
    int p = blockIdx.x * 128 + tid;       // 0 .. 524287
    int b = p >> 18;
    int hw = p & (PLANE - 1);
    const float* src = sc + (size_t)b * 64 * PLANE + hw;
    float sum = 0.f, sq = 0.f;
    #pragma unroll 8
    for (int c = 0; c < 64; ++c) {
        float v = src[(size_t)c * PLANE];
        tile[c * 128 + tid] = v;
        sum += v; sq += v * v;
    }
    float mu = sum * (1.0f / 64.0f);
    float var = sq * (1.0f / 64.0f) - mu * mu;
    float rstd = rsqrtf(var + 1e-5f);
    float* dst = sn + (size_t)b * 64 * PLANE + hw;
    #pragma unroll 8
    for (int c = 0; c < 64; ++c) {
        float v = tile[c * 128 + tid];
        dst[(size_t)c * PLANE] = (v - mu) * rstd * lnw[c] + lnb[c];
    }
}

// ---------------- K2: depthwise 3x3 (64ch) + BN + GELU ----------------
__global__ __launch_bounds__(256) void k_dw64(const float* __restrict__ in,
                                              const float* __restrict__ wt,
                                              const float* __restrict__ bns,
                                              const float* __restrict__ bnt,
                                              float* __restrict__ out) {
    int idx = blockIdx.x * 256 + threadIdx.x;   // over 2*64*PLANE
    int w = idx & 511;
    int h = (idx >> 9) & 511;
    int bc = idx >> 18;
    int c = bc & 63;
    const float* ip = in + (size_t)bc * PLANE;
    const float* wp = wt + c * 9;
    float acc = 0.f;
    #pragma unroll
    for (int dh = -1; dh <= 1; ++dh) {
        int hh = h + dh; if (hh < 0 || hh > 511) continue;
        #pragma unroll
        for (int dw = -1; dw <= 1; ++dw) {
            int ww = w + dw; if (ww < 0 || ww > 511) continue;
            acc += wp[(dh + 1) * 3 + (dw + 1)] * ip[hh * 512 + ww];
        }
    }
    out[idx] = gelu_f(acc * bns[c] + bnt[c]);
}

// ---------------- setup: pw weights W1/W2 -> bf16 ----------------
__global__ __launch_bounds__(256) void k_wsetup2(const float* __restrict__ W1,
                                                 const float* __restrict__ W2,
                                                 unsigned short* __restrict__ w1b,
                                                 unsigned short* __restrict__ w2b) {
    int tid = blockIdx.x * 256 + threadIdx.x;
    if (tid < 8192) { w1b[tid] = f2bf(W1[tid]); w2b[tid] = f2bf(W2[tid]); }
}

// ---------------- K3 v2: MFMA pw 64->128 (+bias+gelu) split; v = bn(MFMA pw 64->128) ----
// Block = 64 pixels, 4 waves x 16-px tiles. Fragment layout identical to k_proj4
// (verified): A row=lane&15, k=(lane>>4)*8+j; D col=lane&15=px, row=(lane>>4)*4+r.
__global__ __launch_bounds__(256, 4) void k_pw2(
    const float* __restrict__ t1,
    const unsigned short* __restrict__ w1b, const float* __restrict__ b1,
    const unsigned short* __restrict__ w2b,
    const float* __restrict__ vbs, const float* __restrict__ vbt,
    float* __restrict__ k_in, float* __restrict__ v)
{
    __shared__ unsigned short vin[64][88];   // [px][ch] bf16, row 176B (16B-mult)
    __shared__ float epi[64 * 68];
    __shared__ float psl[128], ptl[128], pbl[128];
    int tid = threadIdx.x;
    if (tid < 128) { psl[tid] = vbs[tid]; ptl[tid] = vbt[tid]; pbl[tid] = b1[tid]; }
    int lane = tid & 63, wva = tid >> 6;
    int cl = lane & 15, kg = lane >> 4;
    int p0 = blockIdx.x * 64;
    int b = p0 >> 18;
    int hw0 = p0 & (PLANE - 1);
    int px = wva * 16 + cl;
    const float* tp = t1 + (size_t)b * 64 * PLANE + hw0 + px;
    __syncthreads();

    // ---- B-frags for GEMM1 from global t1, packed to bf16 ----
    unsigned bfr[2][4];
    #pragma unroll
    for (int ks = 0; ks < 2; ++ks)
        #pragma unroll
        for (int jp = 0; jp < 4; ++jp) {
            int c = ks * 32 + kg * 8 + jp * 2;
            float f0 = tp[(size_t)c * PLANE];
            float f1 = tp[(size_t)(c + 1) * PLANE];
            unsigned r;
            asm("v_cvt_pk_bf16_f32 %0,%1,%2" : "=v"(r) : "v"(f0), "v"(f1));
            bfr[ks][jp] = r;
        }

    // ---- GEMM1: 128 x 64px x K64 ----
    f32x4 acc[8];
    #pragma unroll
    for (int mt = 0; mt < 8; ++mt) acc[mt] = (f32x4){0.f, 0.f, 0.f, 0.f};
    #pragma unroll
    for (int ks = 0; ks < 2; ++ks) {
        union { unsigned u[4]; bf16x8 v; } bb;
        bb.u[0] = bfr[ks][0]; bb.u[1] = bfr[ks][1]; bb.u[2] = bfr[ks][2]; bb.u[3] = bfr[ks][3];
        #pragma unroll
        for (int mt = 0; mt < 8; ++mt) {
            bf16x8 af = *(const bf16x8*)(w1b + (size_t)(mt * 16 + cl) * 64 + ks * 32 + kg * 8);
            acc[mt] = __builtin_amdgcn_mfma_f32_16x16x32_bf16(af, bb.v, acc[mt], 0, 0, 0);
        }
    }

    // ---- vin (ch 64..127): bias+gelu -> bf16 LDS [px][ch] ----
    #pragma unroll
    for (int mt = 4; mt < 8; ++mt) {
        float g[4];
        #pragma unroll
        for (int r = 0; r < 4; ++r)
            g[r] = gelu_f(acc[mt][r] + pbl[mt * 16 + kg * 4 + r]);
        unsigned r01, r23;
        asm("v_cvt_pk_bf16_f32 %0,%1,%2" : "=v"(r01) : "v"(g[0]), "v"(g[1]));
        asm("v_cvt_pk_bf16_f32 %0,%1,%2" : "=v"(r23) : "v"(g[2]), "v"(g[3]));
        int ch = (mt - 4) * 16 + kg * 4;
        *(unsigned*)&vin[px][ch]     = r01;
        *(unsigned*)&vin[px][ch + 2] = r23;
    }

    // ---- k_in (ch 0..63): bias+gelu -> LDS transpose -> coalesced stores ----
    __syncthreads();
    #pragma unroll
    for (int mt = 0; mt < 4; ++mt)
        #pragma unroll
        for (int r = 0; r < 4; ++r) {
            int m = mt * 16 + kg * 4 + r;
            epi[m * 68 + px] = gelu_f(acc[mt][r] + pbl[m]);
        }
    __syncthreads();
    float* kb = k_in + (size_t)b * 64 * PLANE + hw0;
    #pragma unroll
    for (int k = 0; k < 4; ++k) {
        int m = wva * 16 + k * 4 + kg;
        float4 vv = *(const float4*)&epi[m * 68 + cl * 4];
        *(float4*)&kb[(size_t)m * PLANE + cl * 4] = vv;
    }

    // ---- GEMM2: v = W2 @ vin ----
    f32x4 acc2[8];
    #pragma unroll
    for (int mt = 0; mt < 8; ++mt) acc2[mt] = (f32x4){0.f, 0.f, 0.f, 0.f};
    #pragma unroll
    for (int ks = 0; ks < 2; ++ks) {
        bf16x8 bb = *(const bf16x8*)&vin[px][ks * 32 + kg * 8];
        #pragma unroll
        for (int mt = 0; mt < 8; ++mt) {
            bf16x8 af = *(const bf16x8*)(w2b + (size_t)(mt * 16 + cl) * 64 + ks * 32 + kg * 8);
            acc2[mt] = __builtin_amdgcn_mfma_f32_16x16x32_bf16(af, bb, acc2[mt], 0, 0, 0);
        }
    }

    // ---- v epilogue: BN + LDS transpose, two 64-ch passes ----
    float* vb = v + (size_t)b * 128 * PLANE + hw0;
    #pragma unroll
    for (int pass = 0; pass < 2; ++pass) {
        __syncthreads();
        #pragma unroll
        for (int mt = pass * 4; mt < pass * 4 + 4; ++mt)
            #pragma unroll
            for (int r = 0; r < 4; ++r) {
                int m = mt * 16 + kg * 4 + r;
                epi[(m - pass * 64) * 68 + px] = acc2[mt][r] * psl[m] + ptl[m];
            }
        __syncthreads();
        #pragma unroll
        for (int k = 0; k < 4; ++k) {
            int ml = wva * 16 + k * 4 + kg;
            float4 vv = *(const float4*)&epi[ml * 68 + cl * 4];
            *(float4*)&vb[(size_t)(pass * 64 + ml) * PLANE + cl * 4] = vv;
        }
    }
}

// ---------------- K4/K5: grouped dw 3x3 (64->128) + BN + GELU, emit row/col pooled sums only ----------------
__global__ __launch_bounds__(512) void k_dwpool(const float* __restrict__ in,
                                                const float* __restrict__ wt,
                                                const float* __restrict__ bns,
                                                const float* __restrict__ bnt,
                                                float* __restrict__ rowsum,   // (B,128,512)
                                                float* __restrict__ colpart) { // (B,128,64,512)
    __shared__ float lred[2][8][8];
    int tid = threadIdx.x;
    int blk = blockIdx.x;            // (b*64+g)*64+hc
    int hc = blk & 63;
    int g  = (blk >> 6) & 63;
    int b  = blk >> 12;
    int o0 = 2 * g, o1 = 2 * g + 1;
    const float* ip = in + ((size_t)b * 64 + g) * PLANE;
    float w0[9], w1[9];
    #pragma unroll
    for (int k = 0; k < 9; ++k) { w0[k] = wt[o0 * 9 + k]; w1[k] = wt[o1 * 9 + k]; }
    float s0 = bns[o0], t0 = bnt[o0], s1 = bns[o1], tt1 = bnt[o1];
    int wx = tid;
    float ca0 = 0.f, ca1 = 0.f;
    int lane = tid & 63, wv = tid >> 6;
    for (int r = 0; r < 8; ++r) {
        int h = hc * 8 + r;
        float nb[9];
        #pragma unroll
        for (int dh = -1; dh <= 1; ++dh) {
            #pragma unroll
            for (int dw = -1; dw <= 1; ++dw) {
                int hh = h + dh, ww = wx + dw;
                nb[(dh + 1) * 3 + dw + 1] =
                    (hh >= 0 && hh < 512 && ww >= 0 && ww < 512) ? ip[hh * 512 + ww] : 0.f;
            }
        }
        float a0 = 0.f, a1 = 0.f;
        #pragma unroll
        for (int k = 0; k < 9; ++k) { a0 += w0[k] * nb[k]; a1 += w1[k] * nb[k]; }
        a0 = gelu_f(a0 * s0 + t0);
        a1 = gelu_f(a1 * s1 + tt1);
        ca0 += a0; ca1 += a1;
        #pragma unroll
        for (int off = 32; off > 0; off >>= 1) {
            a0 += __shfl_down(a0, off, 64);
            a1 += __shfl_down(a1, off, 64);
        }
        if (lane == 0) { lred[0][r][wv] = a0; lred[1][r][wv] = a1; }
    }
    colpart[(((size_t)b * 128 + o0) * 64 + hc) * 512 + wx] = ca0;
    colpart[(((size_t)b * 128 + o1) * 64 + hc) * 512 + wx] = ca1;
    __syncthreads();
    if (tid < 16) {
        int oo = tid >> 3, r = tid & 7;
        float s = 0.f;
        #pragma unroll
        for (int i = 0; i < 8; ++i) s += lred[oo][r][i];
        int och = oo == 0 ? o0 : o1;
        rowsum[((size_t)b * 128 + och) * 512 + hc * 8 + r] = s;
    }
}

// ---------------- v pooling: row/col sums of v ----------------
__global__ __launch_bounds__(512) void k_vpool(const float* __restrict__ v,
                                               float* __restrict__ rowsum,
                                               float* __restrict__ colpart) {
    __shared__ float lred[8][8];
    int tid = threadIdx.x;
    int blk = blockIdx.x;     // (b*128+c)*64+hc
    int hc = blk & 63;
    int bc = blk >> 6;
    const float* ip = v + (size_t)bc * PLANE;
    float ca = 0.f;
    int lane = tid & 63, wv = tid >> 6;
    for (int r = 0; r < 8; ++r) {
        float a = ip[(hc * 8 + r) * 512 + tid];
        ca += a;
        #pragma unroll
        for (int off = 32; off > 0; off >>= 1) a += __shfl_down(a, off, 64);
        if (lane == 0) lred[r][wv] = a;
    }
    colpart[((size_t)bc * 64 + hc) * 512 + tid] = ca;
    __syncthreads();
    if (tid < 8) {
        float s = 0.f;
        #pragma unroll
        for (int i = 0; i < 8; ++i) s += lred[tid][i];
        rowsum[(size_t)bc * 512 + hc * 8 + tid] = s;
    }
}

// ---------------- reduce col partials (64 chunks) ----------------
__global__ __launch_bounds__(256) void k_colreduce(const float* __restrict__ part,
                                                   float* __restrict__ out, int n) {
    int idx = blockIdx.x * 256 + threadIdx.x;
    if (idx >= n) return;
    int bc = idx >> 9, w = idx & 511;
    const float* pp = part + ((size_t)bc * 64) * 512 + w;
    float s = 0.f;
    #pragma unroll
    for (int p = 0; p < 64; ++p) s += pp[p * 512];
    out[idx] = s;
}

// ---------------- K6: axial attention (row & col), tiny ----------------
__global__ __launch_bounds__(256) void k_attn(const float* __restrict__ qrow,
                                              const float* __restrict__ krow,
                                              const float* __restrict__ vrow,
                                              const float* __restrict__ qcol,
                                              const float* __restrict__ kcol,
                                              const float* __restrict__ vcol,
                                              const float* __restrict__ perq,
                                              const float* __restrict__ perk,
                                              const float* __restrict__ pecq,
                                              const float* __restrict__ peck,
                                              float* __restrict__ arow,
                                              float* __restrict__ acol) {
    __shared__ float P[16][17];
    int blk = blockIdx.x;   // b*16 + head*2 + axis
    int axis = blk & 1;
    int head = (blk >> 1) & 7;
    int b = blk >> 4;
    const float* qs = axis ? qcol : qrow;
    const float* ks = axis ? kcol : krow;
    const float* vs = axis ? vcol : vrow;
    const float* peq = axis ? pecq : perq;
    const float* pek = axis ? peck : perk;
    float* out = axis ? acol : arow;
    int tid = threadIdx.x;
    int i = tid >> 4, j = tid & 15;
    int ci = head * 16 + i, cj = head * 16 + j;
    const float* qp = qs + ((size_t)b * 128 + ci) * 512;
    const float* kp = ks + ((size_t)b * 128 + cj) * 512;
    const float* qe = peq + ci * 512;
    const float* ke = pek + cj * 512;
    float s = 0.f;
    for (int n = 0; n < 512; ++n) {
        float qv = qp[n] * (1.f / 512.f) + qe[n];
        float kv = kp[n] * (1.f / 512.f) + ke[n];
        s += qv * kv;
    }
    s *= 0.0441941738241592203f;   // 1/sqrt(512)
    P[i][j] = s;
    __syncthreads();
    if (tid < 16) {
        float mx = -1e30f;
        #pragma unroll
        for (int jj = 0; jj < 16; ++jj) mx = fmaxf(mx, P[tid][jj]);
        float e[16];
        float sum = 0.f;
        #pragma unroll
        for (int jj = 0; jj < 16; ++jj) { e[jj] = expf(P[tid][jj] - mx); sum += e[jj]; }
        float inv = 1.f / sum;
        #pragma unroll
        for (int jj = 0; jj < 16; ++jj) P[tid][jj] = e[jj] * inv;
    }
    __syncthreads();
    for (int idx = tid; idx < 16 * 512; idx += 256) {
        int ii = idx >> 9, n = idx & 511;
        const float* vb = vs + ((size_t)b * 128 + head * 16) * 512 + n;
        float acc = 0.f;
        #pragma unroll
        for (int jj = 0; jj < 16; ++jj) acc += P[ii][jj] * vb[jj * 512] * (1.f / 512.f);
        out[((size_t)b * 128 + head * 16 + ii) * 512 + n] = acc;
    }
}

// ---------------- setup: shuffled pw weights -> bf16 ----------------
__global__ __launch_bounds__(256) void k_wsetup(const float* __restrict__ pww,
                                                unsigned short* __restrict__ wsh) {
    int tid = blockIdx.x * 256 + threadIdx.x;
    if (tid >= 64 * 320) return;
    int m = tid / 320, src = tid % 320;
    int o = (src % 5) * 64 + src / 5;     // shuffled-channel index fed by cat channel `src`
    wsh[m * 320 + src] = f2bf(pww[m * 320 + o]);
}

// ---------------- setup: attn fold map AW[b][c][col] ----------------
__global__ __launch_bounds__(256) void k_awsetup(const float* __restrict__ pdw,
                                                 const float* __restrict__ aprw,
                                                 const float* __restrict__ apcw,
                                                 const float* __restrict__ arow,
                                                 const float* __restrict__ acol,
                                                 float* __restrict__ aw) {
    int idx = blockIdx.x * 256 + threadIdx.x;   // 2*128*512
    if (idx >= 2 * 128 * 512) return;
    int col = idx & 511;
    int c   = (idx >> 9) & 127;
    int b   = idx >> 16;
    int src = 64 + c;
    int o = (src % 5) * 64 + src / 5;
    const float* wd = pdw + o * 9;
    float ws0 = wd[0] + wd[3] + wd[6];
    float ws1 = wd[1] + wd[4] + wd[7];
    float ws2 = wd[2] + wd[5] + wd[8];
    const float* ar = arow + ((size_t)b * 128 + c) * 512;
    const float* ac = acol + ((size_t)b * 128 + c) * 512;
    float apr = aprw[c], apc = apcw[c];
    float sum = ws1 * (apr * ar[col] + apc * ac[col]);
    if (col > 0)   sum += ws0 * (apr * ar[col - 1] + apc * ac[col - 1]);
    if (col < 511) sum += ws2 * (apr * ar[col + 1] + apc * ac[col + 1]);
    aw[idx] = sum;
}

// ---------------- K7 v4: strip-of-4 frag-direct conv + MFMA + LDS-coalesced epilogue ----
template<bool HE, bool WE>
__device__ __forceinline__ void conv2x(const float* __restrict__ p,
    const float* wlA, const float* wlP,
    const int* hrow, const float* rv, int ls, int rs, float cv0, float cv2,
    float outA[4], float outP[4])
{
    float a0,a1,a2, b0,b1,b2, c0,c1,c2;
    const float* q = p + hrow[0]*512;
    if (WE) { a0=q[ls]*cv0; a1=q[0]; a2=q[rs]*cv2; } else { a0=q[-1]; a1=q[0]; a2=q[1]; }
    q = p + hrow[1]*512;
    if (WE) { b0=q[ls]*cv0; b1=q[0]; b2=q[rs]*cv2; } else { b0=q[-1]; b1=q[0]; b2=q[1]; }
    q = p + hrow[2]*512;
    if (WE) { c0=q[ls]*cv0; c1=q[0]; c2=q[rs]*cv2; } else { c0=q[-1]; c1=q[0]; c2=q[1]; }
    #pragma unroll
    for (int hs = 0; hs < 4; ++hs) {
        float sA0 = wlA[0]*a0 + wlA[1]*a1 + wlA[2]*a2;
        float sA1 = wlA[3]*b0 + wlA[4]*b1 + wlA[5]*b2;
        float sA2 = wlA[6]*c0 + wlA[7]*c1 + wlA[8]*c2;
        float sP0 = wlP[0]*a0 + wlP[1]*a1 + wlP[2]*a2;
        float sP1 = wlP[3]*b0 + wlP[4]*b1 + wlP[5]*b2;
        float sP2 = wlP[6]*c0 + wlP[7]*c1 + wlP[8]*c2;
        if (HE) {
            outA[hs] = rv[hs]*sA0 + sA1 + rv[hs+2]*sA2 + wlA[9];
            outP[hs] = rv[hs]*sP0 + sP1 + rv[hs+2]*sP2 + wlP[9];
        } else {
            outA[hs] = sA0 + sA1 + sA2 + wlA[9];
            outP[hs] = sP0 + sP1 + sP2 + wlP[9];
        }
        if (hs < 3) {
            a0=b0; a1=b1; a2=b2; b0=c0; b1=c1; b2=c2;
            q = p + hrow[hs+3]*512;
            if (WE) { c0=q[ls]*cv0; c1=q[0]; c2=q[rs]*cv2; } else { c0=q[-1]; c1=q[0]; c2=q[1]; }
        }
    }
}

template<bool HE, bool WE>
__device__ __forceinline__ void conv1x(const float* __restrict__ p,
    const float* wl,
    const int* hrow, const float* rv, int ls, int rs, float cv0, float cv2,
    float out[4])
{
    float a0,a1,a2, b0,b1,b2, c0,c1,c2;
    const float* q = p + hrow[0]*512;
    if (WE) { a0=q[ls]*cv0; a1=q[0]; a2=q[rs]*cv2; } else { a0=q[-1]; a1=q[0]; a2=q[1]; }
    q = p + hrow[1]*512;
    if (WE) { b0=q[ls]*cv0; b1=q[0]; b2=q[rs]*cv2; } else { b0=q[-1]; b1=q[0]; b2=q[1]; }
    q = p + hrow[2]*512;
    if (WE) { c0=q[ls]*cv0; c1=q[0]; c2=q[rs]*cv2; } else { c0=q[-1]; c1=q[0]; c2=q[1]; }
    #pragma unroll
    for (int hs = 0; hs < 4; ++hs) {
        float s0 = wl[0]*a0 + wl[1]*a1 + wl[2]*a2;
        float s1 = wl[3]*b0 + wl[4]*b1 + wl[5]*b2;
        float s2 = wl[6]*c0 + wl[7]*c1 + wl[8]*c2;
        out[hs] = (HE ? (rv[hs]*s0 + s1 + rv[hs+2]*s2) : (s0 + s1 + s2)) + wl[9];
        if (hs < 3) {
            a0=b0; a1=b1; a2=b2; b0=c0; b1=c1; b2=c2;
            q = p + hrow[hs+3]*512;
            if (WE) { c0=q[ls]*cv0; c1=q[0]; c2=q[rs]*cv2; } else { c0=q[-1]; c1=q[0]; c2=q[1]; }
        }
    }
}

template<bool HE, bool WE>
__device__ __forceinline__ void proj4_core(
    int h0, int wwbase, float* epi, const float* dwl,
    const float* __restrict__ xb, const float* __restrict__ vbp,
    const float* __restrict__ arb, const float* __restrict__ acb,
    const float* __restrict__ aprw, const float* __restrict__ apcw,
    const float* __restrict__ awb,
    const unsigned short* __restrict__ wsh, const float* __restrict__ pwb,
    float* __restrict__ outb)
{
    int tid = threadIdx.x;
    int lane = tid & 63, wva = tid >> 6;
    int cl = lane & 15, kg = lane >> 4;
    int ww = wwbase + wva * 16 + cl;

    int hrow[6]; float rv[6];
    #pragma unroll
    for (int i = 0; i < 6; ++i) {
        int r = h0 - 1 + i;
        float va = 1.f;
        if (HE) { if (r < 0) { r = 0; va = 0.f; } if (r > 511) { r = 511; va = 0.f; } }
        hrow[i] = r; rv[i] = va;
    }
    int ls = -1, rs = 1; float cv0 = 1.f, cv2 = 1.f;
    if (WE) {
        if (ww == 0)   { ls = 1;  cv0 = 0.f; }
        if (ww == 511) { rs = -1; cv2 = 0.f; }
    }

    f32x4 acc[4][4];
    #pragma unroll
    for (int hs = 0; hs < 4; ++hs)
        #pragma unroll
        for (int mt = 0; mt < 4; ++mt)
            acc[hs][mt] = (f32x4){0.f, 0.f, 0.f, 0.f};

    // ---- x slices (ks 0,1) ----
    #pragma unroll
    for (int ks = 0; ks < 2; ++ks) {
        unsigned bp[4][4];
        #pragma unroll
        for (int jp = 0; jp < 4; ++jp) {
            float cj0[4], cj1[4];
            int ch = ks * 32 + kg * 8 + jp * 2;
            conv1x<HE,WE>(xb + (size_t)ch * PLANE + ww, dwl + ch * 12,
                          hrow, rv, ls, rs, cv0, cv2, cj0);
            conv1x<HE,WE>(xb + (size_t)(ch+1) * PLANE + ww, dwl + (ch+1) * 12,
                          hrow, rv, ls, rs, cv0, cv2, cj1);
            #pragma unroll
            for (int hs = 0; hs < 4; ++hs) {
                float g0 = gelu_f(cj0[hs]), g1 = gelu_f(cj1[hs]);
                unsigned r;
                asm("v_cvt_pk_bf16_f32 %0,%1,%2" : "=v"(r) : "v"(g0), "v"(g1));
                bp[hs][jp] = r;
            }
        }
        #pragma unroll
        for (int mt = 0; mt < 4; ++mt) {
            bf16x8 af = *(const bf16x8*)(wsh + (size_t)(mt * 16 + cl) * 320 + ks * 32 + kg * 8);
            #pragma unroll
            for (int hs = 0; hs < 4; ++hs) {
                union { unsigned u[4]; bf16x8 v; } bb;
                bb.u[0] = bp[hs][0]; bb.u[1] = bp[hs][1]; bb.u[2] = bp[hs][2]; bb.u[3] = bp[hs][3];
                acc[hs][mt] = __builtin_amdgcn_mfma_f32_16x16x32_bf16(af, bb.v, acc[hs][mt], 0, 0, 0);
            }
        }
    }

    // ---- v slices: fused attn (slice 2+vks) + plain (slice 6+vks) ----
    #pragma unroll
    for (int vks = 0; vks < 4; ++vks) {
        unsigned bpA[4][4], bpP[4][4];
        #pragma unroll
        for (int jp = 0; jp < 4; ++jp) {
            float cA[2][4], cP[2][4];
            #pragma unroll
            for (int e = 0; e < 2; ++e) {
                int c = vks * 32 + kg * 8 + jp * 2 + e;
                const float* wlA = dwl + (64 + c) * 12;
                conv2x<HE,WE>(vbp + (size_t)c * PLANE + ww, wlA, dwl + (192 + c) * 12,
                              hrow, rv, ls, rs, cv0, cv2, cA[e], cP[e]);
                float awv = awb[(size_t)c * 512 + ww];
                #pragma unroll
                for (int hs = 0; hs < 4; ++hs) {
                    if (!HE) {
                        cA[e][hs] += awv;
                    } else {
                        if (rv[hs] + rv[hs + 2] == 2.f) {
                            cA[e][hs] += awv;
                        } else {
                            const float* arp = arb + (size_t)c * 512 + ww;
                            const float* acp = acb + (size_t)c * 512 + ww;
                            float apr = aprw[c], apc = apcw[c];
                            float aa0 = (apr * arp[ls] + apc * acp[ls]) * cv0;
                            float aa1 =  apr * arp[0]  + apc * acp[0];
                            float aa2 = (apr * arp[rs] + apc * acp[rs]) * cv2;
                            float wd0 = rv[hs]*wlA[0] + wlA[3] + rv[hs+2]*wlA[6];
                            float wd1 = rv[hs]*wlA[1] + wlA[4] + rv[hs+2]*wlA[7];
                            float wd2 = rv[hs]*wlA[2] + wlA[5] + rv[hs+2]*wlA[8];
                            cA[e][hs] += wd0*aa0 + wd1*aa1 + wd2*aa2;
                        }
                    }
                }
            }
            #pragma unroll
            for (int hs = 0; hs < 4; ++hs) {
                float gA0 = gelu_f(cA[0][hs]), gA1 = gelu_f(cA[1][hs]);
                float gP0 = gelu_f(cP[0][hs]), gP1 = gelu_f(cP[1][hs]);
                unsigned ra, rp;
                asm("v_cvt_pk_bf16_f32 %0,%1,%2" : "=v"(ra) : "v"(gA0), "v"(gA1));
                asm("v_cvt_pk_bf16_f32 %0,%1,%2" : "=v"(rp) : "v"(gP0), "v"(gP1));
                bpA[hs][jp] = ra; bpP[hs][jp] = rp;
            }
        }
        #pragma unroll
        for (int mt = 0; mt < 4; ++mt) {
            bf16x8 afA = *(const bf16x8*)(wsh + (size_t)(mt * 16 + cl) * 320 + (2 + vks) * 32 + kg * 8);
            #pragma unroll
            for (int hs = 0; hs < 4; ++hs) {
                union { unsigned u[4]; bf16x8 v; } bb;
                bb.u[0] = bpA[hs][0]; bb.u[1] = bpA[hs][1]; bb.u[2] = bpA[hs][2]; bb.u[3] = bpA[hs][3];
                acc[hs][mt] = __builtin_amdgcn_mfma_f32_16x16x32_bf16(afA, bb.v, acc[hs][mt], 0, 0, 0);
            }
            bf16x8 afP = *(const bf16x8*)(wsh + (size_t)(mt * 16 + cl) * 320 + (6 + vks) * 32 + kg * 8);
            #pragma unroll
            for (int hs = 0; hs < 4; ++hs) {
                union { unsigned u[4]; bf16x8 v; } bb;
                bb.u[0] = bpP[hs][0]; bb.u[1] = bpP[hs][1]; bb.u[2] = bpP[hs][2]; bb.u[3] = bpP[hs][3];
                acc[hs][mt] = __builtin_amdgcn_mfma_f32_16x16x32_bf16(afP, bb.v, acc[hs][mt], 0, 0, 0);
            }
        }
    }

    // ---- epilogue: LDS transpose -> 256B-contiguous float4 stores ----
    #pragma unroll
    for (int hs = 0; hs < 4; ++hs) {
        __syncthreads();
        #pragma unroll
        for (int mt = 0; mt < 4; ++mt)
            #pragma unroll
            for (int r = 0; r < 4; ++r) {
                int m = mt * 16 + kg * 4 + r;
                epi[m * 68 + wva * 16 + cl] = gelu_f(acc[hs][mt][r] + pwb[m]);
            }
        __syncthreads();
        #pragma unroll
        for (int k = 0; k < 4; ++k) {
            int m = wva * 16 + k * 4 + kg;
            float4 vv = *(const float4*)&epi[m * 68 + cl * 4];
            *(float4*)&outb[(size_t)m * PLANE + (size_t)(h0 + hs) * 512 + wwbase + cl * 4] = vv;
        }
    }
}

__global__ __launch_bounds__(256, 3) void k_proj4(
    const float* __restrict__ x, const float* __restrict__ v,
    const float* __restrict__ arow, const float* __restrict__ acol,
    const float* __restrict__ aprw, const float* __restrict__ apcw,
    const float* __restrict__ dww, const float* __restrict__ dwb,
    const unsigned short* __restrict__ wsh, const float* __restrict__ pwb,
    const float* __restrict__ aw, float* __restrict__ out)
{
    __shared__ float dwl[320 * 12];   // 15,360 B
    __shared__ float epi[64 * 68];    // 17,408 B
    int tid = threadIdx.x;
    for (int i = tid; i < 3200; i += 256) {
        int src = i / 10, k = i - src * 10;
        int o = (src % 5) * 64 + src / 5;
        dwl[src * 12 + k] = (k < 9) ? dww[o * 9 + k] : dwb[o];
    }
    __syncthreads();
    // XCD swizzle: contiguous strip chunks per XCD
    int flat = blockIdx.x;                 // 0..2047
    int nf = (flat & 7) * 256 + (flat >> 3);
    int bx = nf & 7;
    int s  = (nf >> 3) & 127;
    int b  = nf >> 10;
    int h0 = s * 4, wwbase = bx * 64;
    const float* xb  = x + (size_t)b * 64 * PLANE;
    const float* vbp = v + (size_t)b * 128 * PLANE;
    const float* arb = arow + (size_t)b * 128 * 512;
    const float* acb = acol + (size_t)b * 128 * 512;
    const float* awb = aw + (size_t)b * 128 * 512;
    float* outb = out + (size_t)b * 64 * PLANE;
    bool HEr = (s == 0) || (s == 127);
    bool WEr = (bx == 0) || (bx == 7);
    if (!HEr && !WEr)
        proj4_core<false,false>(h0, wwbase, epi, dwl, xb, vbp, arb, acb, aprw, apcw, awb, wsh, pwb, outb);
    else if (!HEr)
        proj4_core<false,true >(h0, wwbase, epi, dwl, xb, vbp, arb, acb, aprw, apcw, awb, wsh, pwb, outb);
    else
        proj4_core<true ,true >(h0, wwbase, epi, dwl, xb, vbp, arb, acb, aprw, apcw, awb, wsh, pwb, outb);
}

extern "C" void kernel_launch(void* const* d_in, const int* in_sizes, int n_in,
                              void* d_out, int out_size, void* d_ws, size_t ws_size,
                              hipStream_t stream) {
    const float* x    = (const float*)d_in[0];
    const float* sc   = (const float*)d_in[1];
    const float* lnw  = (const float*)d_in[2];
    const float* lnb  = (const float*)d_in[3];
    const float* ddw  = (const float*)d_in[4];
    const float* dbs  = (const float*)d_in[5];
    const float* dbt  = (const float*)d_in[6];
    const float* pw1  = (const float*)d_in[7];
    const float* pb1  = (const float*)d_in[8];
    const float* qdw  = (const float*)d_in[9];
    const float* qbs  = (const float*)d_in[10];
    const float* qbt  = (const float*)d_in[11];
    const float* kdw  = (const float*)d_in[12];
    const float* kbs  = (const float*)d_in[13];
    const float* kbt  = (const float*)d_in[14];
    const float* vpw  = (const float*)d_in[15];
    const float* vbs  = (const float*)d_in[16];
    const float* vbt  = (const float*)d_in[17];
    const float* pdw  = (const float*)d_in[18];
    const float* pdb  = (const float*)d_in[19];
    const float* ppw  = (const float*)d_in[20];
    const float* ppb  = (const float*)d_in[21];
    const float* perq = (const float*)d_in[22];
    const float* perk = (const float*)d_in[23];
    const float* pecq = (const float*)d_in[24];
    const float* peck = (const float*)d_in[25];
    const float* aprw = (const float*)d_in[26];
    const float* apcw = (const float*)d_in[27];

    // d_out doubles as scratch: sn (K1->K2), then k_in (K3->K4), then final out (K7).
    float* bufA = (float*)d_out;         // 33,554,432 floats
    float* ws   = (float*)d_ws;
    float* bufB = ws;                    // 33,554,432 floats: t1, later col partials
    float* bufV = ws + 33554432;         // 67,108,864 floats: v
    float* sm   = ws + 100663296;        // pooled vectors (1,048,576 floats)
    float* qrow = sm;
    float* krow = sm + 131072;
    float* vrow = sm + 262144;
    float* qcol = sm + 393216;
    float* kcol = sm + 524288;
    float* vcol = sm + 655360;
    float* arow = sm + 786432;
    float* acol = sm + 917504;
    unsigned short* wsh = (unsigned short*)(ws + 101711872);   // 20480 bf16 = 10240 floats
    float* aw   = ws + 101722112;        // 131,072 floats attn fold map
    unsigned short* w1b = (unsigned short*)(ws + 101853184);   // 8192 bf16 = 4096 floats
    unsigned short* w2b = (unsigned short*)(ws + 101857280);   // 8192 bf16
    float* qcp  = bufB;                  // col partials alias dead t1 buffer
    float* kcp  = bufB + 8388608;
    float* vcp  = bufB + 16777216;

    k_wsetup <<<80,   256, 0, stream>>>(ppw, wsh);
    k_wsetup2<<<32,   256, 0, stream>>>(pw1, vpw, w1b, w2b);
    k_ln   <<<4096,   128, 0, stream>>>(sc, lnw, lnb, bufA);
    k_dw64 <<<131072, 256, 0, stream>>>(bufA, ddw, dbs, dbt, bufB);
    k_pw2  <<<8192,   256, 0, stream>>>(bufB, w1b, pb1, w2b, vbs, vbt, bufA, bufV);
    k_dwpool<<<8192,  512, 0, stream>>>(x,    qdw, qbs, qbt, qrow, qcp);
    k_dwpool<<<8192,  512, 0, stream>>>(bufA, kdw, kbs, kbt, krow, kcp);
    k_vpool<<<16384,  512, 0, stream>>>(bufV, vrow, vcp);
    k_colreduce<<<512, 256, 0, stream>>>(qcp, qcol, 131072);
    k_colreduce<<<512, 256, 0, stream>>>(kcp, kcol, 131072);
    k_colreduce<<<512, 256, 0, stream>>>(vcp, vcol, 131072);
    k_attn <<<32,     256, 0, stream>>>(qrow, krow, vrow, qcol, kcol, vcol,
                                        perq, perk, pecq, peck, arow, acol);
    k_awsetup<<<512,  256, 0, stream>>>(pdw, aprw, apcw, arow, acol, aw);
    k_proj4<<<2048,   256, 0, stream>>>(x, bufV, arow, acol, aprw, apcw,
                                        pdw, pdb, wsh, ppb, aw, (float*)d_out);
}

// Round 9
// 1038.184 us; speedup vs baseline: 2.5904x; 1.1876x over previous
//
#include <hip/hip_runtime.h>
#include <math.h>

#define PLANE (512*512)

typedef short bf16x8 __attribute__((ext_vector_type(8)));
typedef float f32x4 __attribute__((ext_vector_type(4)));

// fast GELU: 0.5*x*(1+erf(x/sqrt(2))), erf via Abramowitz-Stegun 7.1.26 (|err|<=1.5e-7)
__device__ __forceinline__ float gelu_f(float x) {
    float ax = fabsf(x) * 0.70710678118654752440f;   // z = |x|/sqrt(2)
    float t = __builtin_amdgcn_rcpf(1.0f + 0.3275911f * ax);
    float poly = t * (0.254829592f + t * (-0.284496736f + t * (1.421413741f
               + t * (-1.453152027f + t * 1.061405429f))));
    float e = __expf(-ax * ax);
    float er = 1.0f - poly * e;
    er = copysignf(er, x);
    return 0.5f * x * (1.0f + er);
}

__device__ __forceinline__ unsigned short f2bf(float f) {
    union { float f; unsigned u; } v; v.f = f;
    unsigned r = v.u + 0x7FFFu + ((v.u >> 16) & 1u);
    return (unsigned short)(r >> 16);
}

// ---------------- K1a: LayerNorm stats per pixel: P=rstd, Q=-mu*rstd ----------------
__global__ __launch_bounds__(256) void k_lnstats(const float* __restrict__ sc,
                                                 float* __restrict__ Pb,
                                                 float* __restrict__ Qb) {
    int p = blockIdx.x * 256 + threadIdx.x;      // 0 .. 524287
    int b = p >> 18;
    int hw = p & (PLANE - 1);
    const float* src = sc + (size_t)b * 64 * PLANE + hw;
    float sum = 0.f, sq = 0.f;
    #pragma unroll 8
    for (int c = 0; c < 64; ++c) {
        float v = src[(size_t)c * PLANE];
        sum += v; sq += v * v;
    }
    float mu = sum * (1.0f / 64.0f);
    float var = sq * (1.0f / 64.0f) - mu * mu;
    float rstd = rsqrtf(var + 1e-5f);
    Pb[p] = rstd;
    Qb[p] = -mu * rstd;
}

// ---------------- K1b: fused LN + depthwise 3x3 + BN + GELU -> packed bf16 t1 ----------------
// conv(sn) = lnw_c * sum_valid w*(raw*P + Q) + lnb_c * sum_valid w  (zero padding exact)
__global__ __launch_bounds__(256) void k_dw64ln(const float* __restrict__ sc,
                                                const float* __restrict__ dww,
                                                const float* __restrict__ lnw,
                                                const float* __restrict__ lnb,
                                                const float* __restrict__ bns,
                                                const float* __restrict__ bnt,
                                                const float* __restrict__ Pb,
                                                const float* __restrict__ Qb,
                                                unsigned* __restrict__ t1b) {
    int p = blockIdx.x * 256 + threadIdx.x;      // pixel
    int b = p >> 18;
    int hw = p & (PLANE - 1);
    int h = hw >> 9, w = hw & 511;
    int tapoff[9]; float Pt[9], Qt[9], vm[9];
    const float* Pp = Pb + (size_t)b * PLANE;
    const float* Qp = Qb + (size_t)b * PLANE;
    #pragma unroll
    for (int dh = -1; dh <= 1; ++dh)
        #pragma unroll
        for (int dw = -1; dw <= 1; ++dw) {
            int k = (dh + 1) * 3 + dw + 1;
            int hh = h + dh, ww = w + dw;
            bool ok = (hh >= 0 && hh < 512 && ww >= 0 && ww < 512);
            int hc = ok ? hh : h, wc = ok ? ww : w;
            int off = hc * 512 + wc;
            tapoff[k] = off;
            vm[k] = ok ? 1.f : 0.f;
            Pt[k] = Pp[off]; Qt[k] = Qp[off];
        }
    const float* scb = sc + (size_t)b * 64 * PLANE;
    unsigned* ob = t1b + (size_t)b * 32 * PLANE + hw;
    for (int c2 = 0; c2 < 32; ++c2) {
        float g[2];
        #pragma unroll
        for (int e = 0; e < 2; ++e) {
            int c = c2 * 2 + e;
            const float* wp = dww + c * 9;
            const float* cp = scb + (size_t)c * PLANE;
            float conv = 0.f, wsum = 0.f;
            #pragma unroll
            for (int k = 0; k < 9; ++k) {
                float wv = wp[k];
                float raw = cp[tapoff[k]];
                conv = fmaf(wv, fmaf(raw, Pt[k], Qt[k]) * vm[k], conv);
                wsum = fmaf(wv, vm[k], wsum);
            }
            float a = lnw[c] * conv + lnb[c] * wsum;
            g[e] = gelu_f(a * bns[c] + bnt[c]);
        }
        unsigned r;
        asm("v_cvt_pk_bf16_f32 %0,%1,%2" : "=v"(r) : "v"(g[0]), "v"(g[1]));
        ob[(size_t)c2 * PLANE] = r;
    }
}

// ---------------- setup: pw weights W1/W2 -> bf16 ----------------
__global__ __launch_bounds__(256) void k_wsetup2(const float* __restrict__ W1,
                                                 const float* __restrict__ W2,
                                                 unsigned short* __restrict__ w1b,
                                                 unsigned short* __restrict__ w2b) {
    int tid = blockIdx.x * 256 + threadIdx.x;
    if (tid < 8192) { w1b[tid] = f2bf(W1[tid]); w2b[tid] = f2bf(W2[tid]); }
}

// ---------------- K3 v2: MFMA pw 64->128 (+bias+gelu) split; v = bn(MFMA pw 64->128) ----
__global__ __launch_bounds__(256, 4) void k_pw2(
    const unsigned* __restrict__ t1b,
    const unsigned short* __restrict__ w1b, const float* __restrict__ b1,
    const unsigned short* __restrict__ w2b,
    const float* __restrict__ vbs, const float* __restrict__ vbt,
    float* __restrict__ k_in, float* __restrict__ v)
{
    __shared__ unsigned short vin[64][88];   // [px][ch] bf16
    __shared__ float epi[64 * 68];
    __shared__ float psl[128], ptl[128], pbl[128];
    int tid = threadIdx.x;
    if (tid < 128) { psl[tid] = vbs[tid]; ptl[tid] = vbt[tid]; pbl[tid] = b1[tid]; }
    int lane = tid & 63, wva = tid >> 6;
    int cl = lane & 15, kg = lane >> 4;
    int p0 = blockIdx.x * 64;
    int b = p0 >> 18;
    int hw0 = p0 & (PLANE - 1);
    int px = wva * 16 + cl;
    const unsigned* tp = t1b + (size_t)b * 32 * PLANE + hw0 + px;
    __syncthreads();

    // ---- B-frags for GEMM1: packed bf16 pairs direct from t1b ----
    unsigned bfr[2][4];
    #pragma unroll
    for (int ks = 0; ks < 2; ++ks)
        #pragma unroll
        for (int jp = 0; jp < 4; ++jp)
            bfr[ks][jp] = tp[(size_t)(ks * 16 + kg * 4 + jp) * PLANE];

    f32x4 acc[8];
    #pragma unroll
    for (int mt = 0; mt < 8; ++mt) acc[mt] = (f32x4){0.f, 0.f, 0.f, 0.f};
    #pragma unroll
    for (int ks = 0; ks < 2; ++ks) {
        union { unsigned u[4]; bf16x8 v; } bb;
        bb.u[0] = bfr[ks][0]; bb.u[1] = bfr[ks][1]; bb.u[2] = bfr[ks][2]; bb.u[3] = bfr[ks][3];
        #pragma unroll
        for (int mt = 0; mt < 8; ++mt) {
            bf16x8 af = *(const bf16x8*)(w1b + (size_t)(mt * 16 + cl) * 64 + ks * 32 + kg * 8);
            acc[mt] = __builtin_amdgcn_mfma_f32_16x16x32_bf16(af, bb.v, acc[mt], 0, 0, 0);
        }
    }

    #pragma unroll
    for (int mt = 4; mt < 8; ++mt) {
        float g[4];
        #pragma unroll
        for (int r = 0; r < 4; ++r)
            g[r] = gelu_f(acc[mt][r] + pbl[mt * 16 + kg * 4 + r]);
        unsigned r01, r23;
        asm("v_cvt_pk_bf16_f32 %0,%1,%2" : "=v"(r01) : "v"(g[0]), "v"(g[1]));
        asm("v_cvt_pk_bf16_f32 %0,%1,%2" : "=v"(r23) : "v"(g[2]), "v"(g[3]));
        int ch = (mt - 4) * 16 + kg * 4;
        *(unsigned*)&vin[px][ch]     = r01;
        *(unsigned*)&vin[px][ch + 2] = r23;
    }

    __syncthreads();
    #pragma unroll
    for (int mt = 0; mt < 4; ++mt)
        #pragma unroll
        for (int r = 0; r < 4; ++r) {
            int m = mt * 16 + kg * 4 + r;
            epi[m * 68 + px] = gelu_f(acc[mt][r] + pbl[m]);
        }
    __syncthreads();
    float* kb = k_in + (size_t)b * 64 * PLANE + hw0;
    #pragma unroll
    for (int k = 0; k < 4; ++k) {
        int m = wva * 16 + k * 4 + kg;
        float4 vv = *(const float4*)&epi[m * 68 + cl * 4];
        *(float4*)&kb[(size_t)m * PLANE + cl * 4] = vv;
    }

    f32x4 acc2[8];
    #pragma unroll
    for (int mt = 0; mt < 8; ++mt) acc2[mt] = (f32x4){0.f, 0.f, 0.f, 0.f};
    #pragma unroll
    for (int ks = 0; ks < 2; ++ks) {
        bf16x8 bb = *(const bf16x8*)&vin[px][ks * 32 + kg * 8];
        #pragma unroll
        for (int mt = 0; mt < 8; ++mt) {
            bf16x8 af = *(const bf16x8*)(w2b + (size_t)(mt * 16 + cl) * 64 + ks * 32 + kg * 8);
            acc2[mt] = __builtin_amdgcn_mfma_f32_16x16x32_bf16(af, bb, acc2[mt], 0, 0, 0);
        }
    }

    float* vb = v + (size_t)b * 128 * PLANE + hw0;
    #pragma unroll
    for (int pass = 0; pass < 2; ++pass) {
        __syncthreads();
        #pragma unroll
        for (int mt = pass * 4; mt < pass * 4 + 4; ++mt)
            #pragma unroll
            for (int r = 0; r < 4; ++r) {
                int m = mt * 16 + kg * 4 + r;
                epi[(m - pass * 64) * 68 + px] = acc2[mt][r] * psl[m] + ptl[m];
            }
        __syncthreads();
        #pragma unroll
        for (int k = 0; k < 4; ++k) {
            int ml = wva * 16 + k * 4 + kg;
            float4 vv = *(const float4*)&epi[ml * 68 + cl * 4];
            *(float4*)&vb[(size_t)(pass * 64 + ml) * PLANE + cl * 4] = vv;
        }
    }
}

// ---------------- K4/K5: grouped dw 3x3 (64->128) + BN + GELU, emit pooled sums ----------------
__global__ __launch_bounds__(512) void k_dwpool(const float* __restrict__ in,
                                                const float* __restrict__ wt,
                                                const float* __restrict__ bns,
                                                const float* __restrict__ bnt,
                                                float* __restrict__ rowsum,
                                                float* __restrict__ colpart) {
    __shared__ float lred[2][8][8];
    int tid = threadIdx.x;
    int blk = blockIdx.x;
    int hc = blk & 63;
    int g  = (blk >> 6) & 63;
    int b  = blk >> 12;
    int o0 = 2 * g, o1 = 2 * g + 1;
    const float* ip = in + ((size_t)b * 64 + g) * PLANE;
    float w0[9], w1[9];
    #pragma unroll
    for (int k = 0; k < 9; ++k) { w0[k] = wt[o0 * 9 + k]; w1[k] = wt[o1 * 9 + k]; }
    float s0 = bns[o0], t0 = bnt[o0], s1 = bns[o1], tt1 = bnt[o1];
    int wx = tid;
    float ca0 = 0.f, ca1 = 0.f;
    int lane = tid & 63, wv = tid >> 6;
    for (int r = 0; r < 8; ++r) {
        int h = hc * 8 + r;
        float nb[9];
        #pragma unroll
        for (int dh = -1; dh <= 1; ++dh) {
            #pragma unroll
            for (int dw = -1; dw <= 1; ++dw) {
                int hh = h + dh, ww = wx + dw;
                nb[(dh + 1) * 3 + dw + 1] =
                    (hh >= 0 && hh < 512 && ww >= 0 && ww < 512) ? ip[hh * 512 + ww] : 0.f;
            }
        }
        float a0 = 0.f, a1 = 0.f;
        #pragma unroll
        for (int k = 0; k < 9; ++k) { a0 += w0[k] * nb[k]; a1 += w1[k] * nb[k]; }
        a0 = gelu_f(a0 * s0 + t0);
        a1 = gelu_f(a1 * s1 + tt1);
        ca0 += a0; ca1 += a1;
        #pragma unroll
        for (int off = 32; off > 0; off >>= 1) {
            a0 += __shfl_down(a0, off, 64);
            a1 += __shfl_down(a1, off, 64);
        }
        if (lane == 0) { lred[0][r][wv] = a0; lred[1][r][wv] = a1; }
    }
    colpart[(((size_t)b * 128 + o0) * 64 + hc) * 512 + wx] = ca0;
    colpart[(((size_t)b * 128 + o1) * 64 + hc) * 512 + wx] = ca1;
    __syncthreads();
    if (tid < 16) {
        int oo = tid >> 3, r = tid & 7;
        float s = 0.f;
        #pragma unroll
        for (int i = 0; i < 8; ++i) s += lred[oo][r][i];
        int och = oo == 0 ? o0 : o1;
        rowsum[((size_t)b * 128 + och) * 512 + hc * 8 + r] = s;
    }
}

// ---------------- v pooling ----------------
__global__ __launch_bounds__(512) void k_vpool(const float* __restrict__ v,
                                               float* __restrict__ rowsum,
                                               float* __restrict__ colpart) {
    __shared__ float lred[8][8];
    int tid = threadIdx.x;
    int blk = blockIdx.x;
    int hc = blk & 63;
    int bc = blk >> 6;
    const float* ip = v + (size_t)bc * PLANE;
    float ca = 0.f;
    int lane = tid & 63, wv = tid >> 6;
    for (int r = 0; r < 8; ++r) {
        float a = ip[(hc * 8 + r) * 512 + tid];
        ca += a;
        #pragma unroll
        for (int off = 32; off > 0; off >>= 1) a += __shfl_down(a, off, 64);
        if (lane == 0) lred[r][wv] = a;
    }
    colpart[((size_t)bc * 64 + hc) * 512 + tid] = ca;
    __syncthreads();
    if (tid < 8) {
        float s = 0.f;
        #pragma unroll
        for (int i = 0; i < 8; ++i) s += lred[tid][i];
        rowsum[(size_t)bc * 512 + hc * 8 + tid] = s;
    }
}

// ---------------- reduce col partials (merged q/k/v) ----------------
__global__ __launch_bounds__(256) void k_colreduce(const float* __restrict__ part,
                                                   float* __restrict__ out, int n) {
    int idx = blockIdx.x * 256 + threadIdx.x;
    if (idx >= n) return;
    int bc = idx >> 9, w = idx & 511;
    const float* pp = part + ((size_t)bc * 64) * 512 + w;
    float s = 0.f;
    #pragma unroll
    for (int p = 0; p < 64; ++p) s += pp[p * 512];
    out[idx] = s;
}

// ---------------- K6: axial attention ----------------
__global__ __launch_bounds__(256) void k_attn(const float* __restrict__ qrow,
                                              const float* __restrict__ krow,
                                              const float* __restrict__ vrow,
                                              const float* __restrict__ qcol,
                                              const float* __restrict__ kcol,
                                              const float* __restrict__ vcol,
                                              const float* __restrict__ perq,
                                              const float* __restrict__ perk,
                                              const float* __restrict__ pecq,
                                              const float* __restrict__ peck,
                                              float* __restrict__ arow,
                                              float* __restrict__ acol) {
    __shared__ float P[16][17];
    int blk = blockIdx.x;
    int axis = blk & 1;
    int head = (blk >> 1) & 7;
    int b = blk >> 4;
    const float* qs = axis ? qcol : qrow;
    const float* ks = axis ? kcol : krow;
    const float* vs = axis ? vcol : vrow;
    const float* peq = axis ? pecq : perq;
    const float* pek = axis ? peck : perk;
    float* out = axis ? acol : arow;
    int tid = threadIdx.x;
    int i = tid >> 4, j = tid & 15;
    int ci = head * 16 + i, cj = head * 16 + j;
    const float* qp = qs + ((size_t)b * 128 + ci) * 512;
    const float* kp = ks + ((size_t)b * 128 + cj) * 512;
    const float* qe = peq + ci * 512;
    const float* ke = pek + cj * 512;
    float s = 0.f;
    for (int n = 0; n < 512; ++n) {
        float qv = qp[n] * (1.f / 512.f) + qe[n];
        float kv = kp[n] * (1.f / 512.f) + ke[n];
        s += qv * kv;
    }
    s *= 0.0441941738241592203f;
    P[i][j] = s;
    __syncthreads();
    if (tid < 16) {
        float mx = -1e30f;
        #pragma unroll
        for (int jj = 0; jj < 16; ++jj) mx = fmaxf(mx, P[tid][jj]);
        float e[16];
        float sum = 0.f;
        #pragma unroll
        for (int jj = 0; jj < 16; ++jj) { e[jj] = expf(P[tid][jj] - mx); sum += e[jj]; }
        float inv = 1.f / sum;
        #pragma unroll
        for (int jj = 0; jj < 16; ++jj) P[tid][jj] = e[jj] * inv;
    }
    __syncthreads();
    for (int idx = tid; idx < 16 * 512; idx += 256) {
        int ii = idx >> 9, n = idx & 511;
        const float* vb = vs + ((size_t)b * 128 + head * 16) * 512 + n;
        float acc = 0.f;
        #pragma unroll
        for (int jj = 0; jj < 16; ++jj) acc += P[ii][jj] * vb[jj * 512] * (1.f / 512.f);
        out[((size_t)b * 128 + head * 16 + ii) * 512 + n] = acc;
    }
}

// ---------------- setup: shuffled pw weights -> bf16 ----------------
__global__ __launch_bounds__(256) void k_wsetup(const float* __restrict__ pww,
                                                unsigned short* __restrict__ wsh) {
    int tid = blockIdx.x * 256 + threadIdx.x;
    if (tid >= 64 * 320) return;
    int m = tid / 320, src = tid % 320;
    int o = (src % 5) * 64 + src / 5;
    wsh[m * 320 + src] = f2bf(pww[m * 320 + o]);
}

// ---------------- setup: attn fold map AW[b][c][col] ----------------
__global__ __launch_bounds__(256) void k_awsetup(const float* __restrict__ pdw,
                                                 const float* __restrict__ aprw,
                                                 const float* __restrict__ apcw,
                                                 const float* __restrict__ arow,
                                                 const float* __restrict__ acol,
                                                 float* __restrict__ aw) {
    int idx = blockIdx.x * 256 + threadIdx.x;
    if (idx >= 2 * 128 * 512) return;
    int col = idx & 511;
    int c   = (idx >> 9) & 127;
    int b   = idx >> 16;
    int src = 64 + c;
    int o = (src % 5) * 64 + src / 5;
    const float* wd = pdw + o * 9;
    float ws0 = wd[0] + wd[3] + wd[6];
    float ws1 = wd[1] + wd[4] + wd[7];
    float ws2 = wd[2] + wd[5] + wd[8];
    const float* ar = arow + ((size_t)b * 128 + c) * 512;
    const float* ac = acol + ((size_t)b * 128 + c) * 512;
    float apr = aprw[c], apc = apcw[c];
    float sum = ws1 * (apr * ar[col] + apc * ac[col]);
    if (col > 0)   sum += ws0 * (apr * ar[col - 1] + apc * ac[col - 1]);
    if (col < 511) sum += ws2 * (apr * ar[col + 1] + apc * ac[col + 1]);
    aw[idx] = sum;
}

// ---------------- K7 v5: strip-of-2 frag-direct conv + MFMA + LDS-coalesced epilogue ----
template<bool HE, bool WE>
__device__ __forceinline__ void conv2x2(const float* __restrict__ p,
    const float* wlA, const float* wlP,
    const int* hrow, const float* rv, int ls, int rs, float cv0, float cv2,
    float outA[2], float outP[2])
{
    float a0,a1,a2, b0,b1,b2, c0,c1,c2;
    const float* q = p + hrow[0]*512;
    if (WE) { a0=q[ls]*cv0; a1=q[0]; a2=q[rs]*cv2; } else { a0=q[-1]; a1=q[0]; a2=q[1]; }
    q = p + hrow[1]*512;
    if (WE) { b0=q[ls]*cv0; b1=q[0]; b2=q[rs]*cv2; } else { b0=q[-1]; b1=q[0]; b2=q[1]; }
    q = p + hrow[2]*512;
    if (WE) { c0=q[ls]*cv0; c1=q[0]; c2=q[rs]*cv2; } else { c0=q[-1]; c1=q[0]; c2=q[1]; }
    #pragma unroll
    for (int hs = 0; hs < 2; ++hs) {
        float sA0 = wlA[0]*a0 + wlA[1]*a1 + wlA[2]*a2;
        float sA1 = wlA[3]*b0 + wlA[4]*b1 + wlA[5]*b2;
        float sA2 = wlA[6]*c0 + wlA[7]*c1 + wlA[8]*c2;
        float sP0 = wlP[0]*a0 + wlP[1]*a1 + wlP[2]*a2;
        float sP1 = wlP[3]*b0 + wlP[4]*b1 + wlP[5]*b2;
        float sP2 = wlP[6]*c0 + wlP[7]*c1 + wlP[8]*c2;
        if (HE) {
            outA[hs] = rv[hs]*sA0 + sA1 + rv[hs+2]*sA2 + wlA[9];
            outP[hs] = rv[hs]*sP0 + sP1 + rv[hs+2]*sP2 + wlP[9];
        } else {
            outA[hs] = sA0 + sA1 + sA2 + wlA[9];
            outP[hs] = sP0 + sP1 + sP2 + wlP[9];
        }
        if (hs < 1) {
            a0=b0; a1=b1; a2=b2; b0=c0; b1=c1; b2=c2;
            q = p + hrow[3]*512;
            if (WE) { c0=q[ls]*cv0; c1=q[0]; c2=q[rs]*cv2; } else { c0=q[-1]; c1=q[0]; c2=q[1]; }
        }
    }
}

template<bool HE, bool WE>
__device__ __forceinline__ void conv1x2(const float* __restrict__ p,
    const float* wl,
    const int* hrow, const float* rv, int ls, int rs, float cv0, float cv2,
    float out[2])
{
    float a0,a1,a2, b0,b1,b2, c0,c1,c2;
    const float* q = p + hrow[0]*512;
    if (WE) { a0=q[ls]*cv0; a1=q[0]; a2=q[rs]*cv2; } else { a0=q[-1]; a1=q[0]; a2=q[1]; }
    q = p + hrow[1]*512;
    if (WE) { b0=q[ls]*cv0; b1=q[0]; b2=q[rs]*cv2; } else { b0=q[-1]; b1=q[0]; b2=q[1]; }
    q = p + hrow[2]*512;
    if (WE) { c0=q[ls]*cv0; c1=q[0]; c2=q[rs]*cv2; } else { c0=q[-1]; c1=q[0]; c2=q[1]; }
    #pragma unroll
    for (int hs = 0; hs < 2; ++hs) {
        float s0 = wl[0]*a0 + wl[1]*a1 + wl[2]*a2;
        float s1 = wl[3]*b0 + wl[4]*b1 + wl[5]*b2;
        float s2 = wl[6]*c0 + wl[7]*c1 + wl[8]*c2;
        out[hs] = (HE ? (rv[hs]*s0 + s1 + rv[hs+2]*s2) : (s0 + s1 + s2)) + wl[9];
        if (hs < 1) {
            a0=b0; a1=b1; a2=b2; b0=c0; b1=c1; b2=c2;
            q = p + hrow[3]*512;
            if (WE) { c0=q[ls]*cv0; c1=q[0]; c2=q[rs]*cv2; } else { c0=q[-1]; c1=q[0]; c2=q[1]; }
        }
    }
}

template<bool HE, bool WE>
__device__ __forceinline__ void proj5_core(
    int h0, int wwbase, float* epi, const float* dwl,
    const float* __restrict__ xb, const float* __restrict__ vbp,
    const float* __restrict__ arb, const float* __restrict__ acb,
    const float* __restrict__ aprw, const float* __restrict__ apcw,
    const float* __restrict__ awb,
    const unsigned short* __restrict__ wsh, const float* __restrict__ pwb,
    float* __restrict__ outb)
{
    int tid = threadIdx.x;
    int lane = tid & 63, wva = tid >> 6;
    int cl = lane & 15, kg = lane >> 4;
    int ww = wwbase + wva * 16 + cl;

    int hrow[4]; float rv[4];
    #pragma unroll
    for (int i = 0; i < 4; ++i) {
        int r = h0 - 1 + i;
        float va = 1.f;
        if (HE) { if (r < 0) { r = 0; va = 0.f; } if (r > 511) { r = 511; va = 0.f; } }
        hrow[i] = r; rv[i] = va;
    }
    int ls = -1, rs = 1; float cv0 = 1.f, cv2 = 1.f;
    if (WE) {
        if (ww == 0)   { ls = 1;  cv0 = 0.f; }
        if (ww == 511) { rs = -1; cv2 = 0.f; }
    }

    f32x4 acc[2][4];
    #pragma unroll
    for (int hs = 0; hs < 2; ++hs)
        #pragma unroll
        for (int mt = 0; mt < 4; ++mt)
            acc[hs][mt] = (f32x4){0.f, 0.f, 0.f, 0.f};

    // ---- x slices (ks 0,1) ----
    #pragma unroll
    for (int ks = 0; ks < 2; ++ks) {
        unsigned bp[2][4];
        #pragma unroll
        for (int jp = 0; jp < 4; ++jp) {
            float cj0[2], cj1[2];
            int ch = ks * 32 + kg * 8 + jp * 2;
            conv1x2<HE,WE>(xb + (size_t)ch * PLANE + ww, dwl + ch * 12,
                           hrow, rv, ls, rs, cv0, cv2, cj0);
            conv1x2<HE,WE>(xb + (size_t)(ch+1) * PLANE + ww, dwl + (ch+1) * 12,
                           hrow, rv, ls, rs, cv0, cv2, cj1);
            #pragma unroll
            for (int hs = 0; hs < 2; ++hs) {
                float g0 = gelu_f(cj0[hs]), g1 = gelu_f(cj1[hs]);
                unsigned r;
                asm("v_cvt_pk_bf16_f32 %0,%1,%2" : "=v"(r) : "v"(g0), "v"(g1));
                bp[hs][jp] = r;
            }
        }
        #pragma unroll
        for (int mt = 0; mt < 4; ++mt) {
            bf16x8 af = *(const bf16x8*)(wsh + (size_t)(mt * 16 + cl) * 320 + ks * 32 + kg * 8);
            #pragma unroll
            for (int hs = 0; hs < 2; ++hs) {
                union { unsigned u[4]; bf16x8 v; } bb;
                bb.u[0] = bp[hs][0]; bb.u[1] = bp[hs][1]; bb.u[2] = bp[hs][2]; bb.u[3] = bp[hs][3];
                acc[hs][mt] = __builtin_amdgcn_mfma_f32_16x16x32_bf16(af, bb.v, acc[hs][mt], 0, 0, 0);
            }
        }
    }

    // ---- v slices: fused attn (slice 2+vks) + plain (slice 6+vks) ----
    #pragma unroll
    for (int vks = 0; vks < 4; ++vks) {
        unsigned bpA[2][4], bpP[2][4];
        #pragma unroll
        for (int jp = 0; jp < 4; ++jp) {
            float cA[2][2], cP[2][2];
            #pragma unroll
            for (int e = 0; e < 2; ++e) {
                int c = vks * 32 + kg * 8 + jp * 2 + e;
                const float* wlA = dwl + (64 + c) * 12;
                conv2x2<HE,WE>(vbp + (size_t)c * PLANE + ww, wlA, dwl + (192 + c) * 12,
                               hrow, rv, ls, rs, cv0, cv2, cA[e], cP[e]);
                float awv = awb[(size_t)c * 512 + ww];
                #pragma unroll
                for (int hs = 0; hs < 2; ++hs) {
                    if (!HE) {
                        cA[e][hs] += awv;
                    } else {
                        if (rv[hs] + rv[hs + 2] == 2.f) {
                            cA[e][hs] += awv;
                        } else {
                            const float* arp = arb + (size_t)c * 512 + ww;
                            const float* acp = acb + (size_t)c * 512 + ww;
                            float apr = aprw[c], apc = apcw[c];
                            float aa0 = (apr * arp[ls] + apc * acp[ls]) * cv0;
                            float aa1 =  apr * arp[0]  + apc * acp[0];
                            float aa2 = (apr * arp[rs] + apc * acp[rs]) * cv2;
                            float wd0 = rv[hs]*wlA[0] + wlA[3] + rv[hs+2]*wlA[6];
                            float wd1 = rv[hs]*wlA[1] + wlA[4] + rv[hs+2]*wlA[7];
                            float wd2 = rv[hs]*wlA[2] + wlA[5] + rv[hs+2]*wlA[8];
                            cA[e][hs] += wd0*aa0 + wd1*aa1 + wd2*aa2;
                        }
                    }
                }
            }
            #pragma unroll
            for (int hs = 0; hs < 2; ++hs) {
                float gA0 = gelu_f(cA[0][hs]), gA1 = gelu_f(cA[1][hs]);
                float gP0 = gelu_f(cP[0][hs]), gP1 = gelu_f(cP[1][hs]);
                unsigned ra, rp;
                asm("v_cvt_pk_bf16_f32 %0,%1,%2" : "=v"(ra) : "v"(gA0), "v"(gA1));
                asm("v_cvt_pk_bf16_f32 %0,%1,%2" : "=v"(rp) : "v"(gP0), "v"(gP1));
                bpA[hs][jp] = ra; bpP[hs][jp] = rp;
            }
        }
        #pragma unroll
        for (int mt = 0; mt < 4; ++mt) {
            bf16x8 afA = *(const bf16x8*)(wsh + (size_t)(mt * 16 + cl) * 320 + (2 + vks) * 32 + kg * 8);
            #pragma unroll
            for (int hs = 0; hs < 2; ++hs) {
                union { unsigned u[4]; bf16x8 v; } bb;
                bb.u[0] = bpA[hs][0]; bb.u[1] = bpA[hs][1]; bb.u[2] = bpA[hs][2]; bb.u[3] = bpA[hs][3];
                acc[hs][mt] = __builtin_amdgcn_mfma_f32_16x16x32_bf16(afA, bb.v, acc[hs][mt], 0, 0, 0);
            }
            bf16x8 afP = *(const bf16x8*)(wsh + (size_t)(mt * 16 + cl) * 320 + (6 + vks) * 32 + kg * 8);
            #pragma unroll
            for (int hs = 0; hs < 2; ++hs) {
                union { unsigned u[4]; bf16x8 v; } bb;
                bb.u[0] = bpP[hs][0]; bb.u[1] = bpP[hs][1]; bb.u[2] = bpP[hs][2]; bb.u[3] = bpP[hs][3];
                acc[hs][mt] = __builtin_amdgcn_mfma_f32_16x16x32_bf16(afP, bb.v, acc[hs][mt], 0, 0, 0);
            }
        }
    }

    // ---- epilogue: LDS transpose -> 256B-contiguous float4 stores ----
    #pragma unroll
    for (int hs = 0; hs < 2; ++hs) {
        __syncthreads();
        #pragma unroll
        for (int mt = 0; mt < 4; ++mt)
            #pragma unroll
            for (int r = 0; r < 4; ++r) {
                int m = mt * 16 + kg * 4 + r;
                epi[m * 68 + wva * 16 + cl] = gelu_f(acc[hs][mt][r] + pwb[m]);
            }
        __syncthreads();
        #pragma unroll
        for (int k = 0; k < 4; ++k) {
            int m = wva * 16 + k * 4 + kg;
            float4 vv = *(const float4*)&epi[m * 68 + cl * 4];
            *(float4*)&outb[(size_t)m * PLANE + (size_t)(h0 + hs) * 512 + wwbase + cl * 4] = vv;
        }
    }
}

__global__ __launch_bounds__(256, 4) void k_proj5(
    const float* __restrict__ x, const float* __restrict__ v,
    const float* __restrict__ arow, const float* __restrict__ acol,
    const float* __restrict__ aprw, const float* __restrict__ apcw,
    const float* __restrict__ dww, const float* __restrict__ dwb,
    const unsigned short* __restrict__ wsh, const float* __restrict__ pwb,
    const float* __restrict__ aw, float* __restrict__ out)
{
    __shared__ float dwl[320 * 12];   // 15,360 B
    __shared__ float epi[64 * 68];    // 17,408 B
    int tid = threadIdx.x;
    for (int i = tid; i < 3200; i += 256) {
        int src = i / 10, k = i - src * 10;
        int o = (src % 5) * 64 + src / 5;
        dwl[src * 12 + k] = (k < 9) ? dww[o * 9 + k] : dwb[o];
    }
    __syncthreads();
    // XCD swizzle: contiguous strip chunks per XCD
    int flat = blockIdx.x;                 // 0..4095
    int nf = (flat & 7) * 512 + (flat >> 3);
    int bx = nf & 7;
    int s  = (nf >> 3) & 255;
    int b  = nf >> 11;
    int h0 = s * 2, wwbase = bx * 64;
    const float* xb  = x + (size_t)b * 64 * PLANE;
    const float* vbp = v + (size_t)b * 128 * PLANE;
    const float* arb = arow + (size_t)b * 128 * 512;
    const float* acb = acol + (size_t)b * 128 * 512;
    const float* awb = aw + (size_t)b * 128 * 512;
    float* outb = out + (size_t)b * 64 * PLANE;
    bool HEr = (s == 0) || (s == 255);
    bool WEr = (bx == 0) || (bx == 7);
    if (!HEr && !WEr)
        proj5_core<false,false>(h0, wwbase, epi, dwl, xb, vbp, arb, acb, aprw, apcw, awb, wsh, pwb, outb);
    else if (!HEr)
        proj5_core<false,true >(h0, wwbase, epi, dwl, xb, vbp, arb, acb, aprw, apcw, awb, wsh, pwb, outb);
    else
        proj5_core<true ,true >(h0, wwbase, epi, dwl, xb, vbp, arb, acb, aprw, apcw, awb, wsh, pwb, outb);
}

extern "C" void kernel_launch(void* const* d_in, const int* in_sizes, int n_in,
                              void* d_out, int out_size, void* d_ws, size_t ws_size,
                              hipStream_t stream) {
    const float* x    = (const float*)d_in[0];
    const float* sc   = (const float*)d_in[1];
    const float* lnw  = (const float*)d_in[2];
    const float* lnb  = (const float*)d_in[3];
    const float* ddw  = (const float*)d_in[4];
    const float* dbs  = (const float*)d_in[5];
    const float* dbt  = (const float*)d_in[6];
    const float* pw1  = (const float*)d_in[7];
    const float* pb1  = (const float*)d_in[8];
    const float* qdw  = (const float*)d_in[9];
    const float* qbs  = (const float*)d_in[10];
    const float* qbt  = (const float*)d_in[11];
    const float* kdw  = (const float*)d_in[12];
    const float* kbs  = (const float*)d_in[13];
    const float* kbt  = (const float*)d_in[14];
    const float* vpw  = (const float*)d_in[15];
    const float* vbs  = (const float*)d_in[16];
    const float* vbt  = (const float*)d_in[17];
    const float* pdw  = (const float*)d_in[18];
    const float* pdb  = (const float*)d_in[19];
    const float* ppw  = (const float*)d_in[20];
    const float* ppb  = (const float*)d_in[21];
    const float* perq = (const float*)d_in[22];
    const float* perk = (const float*)d_in[23];
    const float* pecq = (const float*)d_in[24];
    const float* peck = (const float*)d_in[25];
    const float* aprw = (const float*)d_in[26];
    const float* apcw = (const float*)d_in[27];

    // d_out doubles as scratch: k_in (k_pw2 -> k_dwpool), then final out (k_proj5).
    float* bufA = (float*)d_out;         // 33,554,432 floats
    float* ws   = (float*)d_ws;
    float* bufB = ws;                    // t1b (bf16 pairs), later col partials
    float* bufV = ws + 33554432;         // 67,108,864 floats: v
    float* sm   = ws + 100663296;        // pooled vectors (1,048,576 floats)
    float* qrow = sm;
    float* krow = sm + 131072;
    float* vrow = sm + 262144;
    float* qcol = sm + 393216;
    float* kcol = sm + 524288;
    float* vcol = sm + 655360;
    float* arow = sm + 786432;
    float* acol = sm + 917504;
    unsigned short* wsh = (unsigned short*)(ws + 101711872);   // 20480 bf16
    float* aw   = ws + 101722112;        // 131,072 floats attn fold map
    unsigned short* w1b = (unsigned short*)(ws + 101853184);   // 8192 bf16
    unsigned short* w2b = (unsigned short*)(ws + 101857280);   // 8192 bf16
    float* Pb   = ws + 101861376;        // 524,288 floats ln rstd
    float* Qb   = ws + 102385664;        // 524,288 floats ln -mu*rstd
    unsigned* t1b = (unsigned*)bufB;     // 16,777,216 uints packed bf16 t1
    float* qcp  = bufB;                  // col partials alias t1b after k_pw2
    float* kcp  = bufB + 8388608;
    float* vcp  = bufB + 16777216;

    k_wsetup <<<80,   256, 0, stream>>>(ppw, wsh);
    k_wsetup2<<<32,   256, 0, stream>>>(pw1, vpw, w1b, w2b);
    k_lnstats<<<2048, 256, 0, stream>>>(sc, Pb, Qb);
    k_dw64ln <<<2048, 256, 0, stream>>>(sc, ddw, lnw, lnb, dbs, dbt, Pb, Qb, t1b);
    k_pw2    <<<8192, 256, 0, stream>>>(t1b, w1b, pb1, w2b, vbs, vbt, bufA, bufV);
    k_dwpool <<<8192, 512, 0, stream>>>(x,    qdw, qbs, qbt, qrow, qcp);
    k_dwpool <<<8192, 512, 0, stream>>>(bufA, kdw, kbs, kbt, krow, kcp);
    k_vpool  <<<16384,512, 0, stream>>>(bufV, vrow, vcp);
    k_colreduce<<<1536,256, 0, stream>>>(qcp, qcol, 393216);
    k_attn   <<<32,   256, 0, stream>>>(qrow, krow, vrow, qcol, kcol, vcol,
                                        perq, perk, pecq, peck, arow, acol);
    k_awsetup<<<512,  256, 0, stream>>>(pdw, aprw, apcw, arow, acol, aw);
    k_proj5  <<<4096, 256, 0, stream>>>(x, bufV, arow, acol, aprw, apcw,
                                        pdw, pdb, wsh, ppb, aw, (float*)d_out);
}